// Round 15
// baseline (120.199 us; speedup 1.0000x reference)
//
#include <hip/hip_runtime.h>
#include <math.h>

// Problem constants
static constexpr int NB   = 16;    // batch
static constexpr int DIM  = 256;   // total channels
static constexpr int CG   = 64;    // global-branch channels
static constexpr int HH   = 64;
static constexpr int WW   = 64;
static constexpr int HW   = HH * WW;   // 4096

__device__ __forceinline__ float mish_fast(float x) {
    float t = __expf(fminf(x, 20.f));
    float p = __builtin_fmaf(t, t, t + t);         // t^2 + 2t
    return x * p * __builtin_amdgcn_rcpf(p + 2.f);
}
__device__ __forceinline__ float silu_f(float x) {
    return x * __builtin_amdgcn_rcpf(1.f + __expf(-x));
}
__device__ __forceinline__ float softplus_fast(float x) {
    return fmaxf(x, 0.f) + __logf(1.f + __expf(-fabsf(x)));
}

// ===========================================================================
// STAGE 1 (bid%3: 0,1 -> A, 2 -> D)
//   role A = wavelet up + channel mean (Haar loads hoisted above mean phase)
//   role D = input projection GEMM, K-chunks of 16 (18.4KB LDS union)
// ===========================================================================
__global__ __launch_bounds__(256) void k_stage1(
    const float* __restrict__ x,
    const float* __restrict__ wav_w, const float* __restrict__ wav_b,
    const float* __restrict__ wav_scale,
    float* __restrict__ up, float* __restrict__ mean,
    const float* __restrict__ in_w,
    float* __restrict__ xi, float* __restrict__ z) {
    __shared__ float smem[4608];
    int bid = blockIdx.x;
    int tid = threadIdx.x;

    if (bid % 3 != 2) {
        // ---------------- role A: wavelet + mean ----------------
        int aid = (bid / 3) * 2 + (bid % 3);   // 0..1023
        int c = aid & 63, b = aid >> 6;
        float* wtb = smem;                 // 4 * (32*34) = 4352
        float* red = smem + 4352;          // 256
        const float* xp = x + ((size_t)b * DIM + c) * HW;

        // hoist Haar dec loads (overlap with the mean phase below)
        int p0h = tid, p1h = tid + 256;
        int h0h = p0h >> 4, w20 = p0h & 15;
        int h1h = p1h >> 4, w21 = p1h & 15;
        float4 top0 = *(const float4*)(xp + (2 * h0h) * 64 + 4 * w20);
        float4 bot0 = *(const float4*)(xp + (2 * h0h + 1) * 64 + 4 * w20);
        float4 top1 = *(const float4*)(xp + (2 * h1h) * 64 + 4 * w21);
        float4 bot1 = *(const float4*)(xp + (2 * h1h + 1) * 64 + 4 * w21);

        // mean of plane (b, 64+c)
        {
            const float4* lp4 = (const float4*)(x + ((size_t)b * DIM + 64 + c) * HW);
            float s = 0.f;
            for (int i = tid; i < 1024; i += 256) {
                float4 v = lp4[i];
                s += (v.x + v.y) + (v.z + v.w);
            }
            red[tid] = s;
            __syncthreads();
            for (int o = 128; o > 0; o >>= 1) {
                if (tid < o) red[tid] += red[tid + o];
                __syncthreads();
            }
            if (tid == 0) mean[b * 64 + c] = red[0] * (1.f / HW);
        }

        // Haar dec writes
        {
            float a0 = top0.x, b0 = top0.y, c0q = bot0.x, d0 = bot0.y;
            float a1 = top0.z, b1 = top0.w, c1q = bot0.z, d1 = bot0.w;
            int base0 = h0h * 34 + 2 * w20;
            *(float2*)(wtb + 0 * 1088 + base0) =
                make_float2(0.5f * (a0 + b0 + c0q + d0), 0.5f * (a1 + b1 + c1q + d1));
            *(float2*)(wtb + 1 * 1088 + base0) =
                make_float2(0.5f * (a0 + b0 - c0q - d0), 0.5f * (a1 + b1 - c1q - d1));
            *(float2*)(wtb + 2 * 1088 + base0) =
                make_float2(0.5f * (a0 - b0 + c0q - d0), 0.5f * (a1 - b1 + c1q - d1));
            *(float2*)(wtb + 3 * 1088 + base0) =
                make_float2(0.5f * (a0 - b0 - c0q + d0), 0.5f * (a1 - b1 - c1q + d1));
            a0 = top1.x; b0 = top1.y; c0q = bot1.x; d0 = bot1.y;
            a1 = top1.z; b1 = top1.w; c1q = bot1.z; d1 = bot1.w;
            int base1 = h1h * 34 + 2 * w21;
            *(float2*)(wtb + 0 * 1088 + base1) =
                make_float2(0.5f * (a0 + b0 + c0q + d0), 0.5f * (a1 + b1 + c1q + d1));
            *(float2*)(wtb + 1 * 1088 + base1) =
                make_float2(0.5f * (a0 + b0 - c0q - d0), 0.5f * (a1 + b1 - c1q - d1));
            *(float2*)(wtb + 2 * 1088 + base1) =
                make_float2(0.5f * (a0 - b0 + c0q - d0), 0.5f * (a1 - b1 + c1q - d1));
            *(float2*)(wtb + 3 * 1088 + base1) =
                make_float2(0.5f * (a0 - b0 - c0q + d0), 0.5f * (a1 - b1 - c1q + d1));
        }
        __syncthreads();

        float wk[4][9], tb[4];
#pragma unroll
        for (int k = 0; k < 4; ++k) {
            int ch = c * 4 + k;
            float sc = wav_scale[ch];
#pragma unroll
            for (int j = 0; j < 9; ++j) wk[k][j] = wav_w[ch * 9 + j] * sc;
            tb[k] = wav_b[ch] * sc;
        }
        float* upp = up + ((size_t)b * CG + c) * HW;
        for (int i = tid; i < 1024; i += 256) {
            int h = i >> 5, w = i & 31;
            float tg[4];
#pragma unroll
            for (int k = 0; k < 4; ++k) {
                float s = tb[k];
#pragma unroll
                for (int dy = -1; dy <= 1; ++dy) {
                    int hh = h + dy;
                    if (hh < 0 || hh >= 32) continue;
#pragma unroll
                    for (int dx = -1; dx <= 1; ++dx) {
                        int wx = w + dx;
                        if (wx < 0 || wx >= 32) continue;
                        s = fmaf(wtb[k * 1088 + hh * 34 + wx], wk[k][(dy + 1) * 3 + (dx + 1)], s);
                    }
                }
                tg[k] = s;
            }
            float u00 = 0.5f * (tg[0] - tg[1] - tg[2] + tg[3]);
            float u01 = 0.5f * (tg[0] - tg[1] + tg[2] - tg[3]);
            float u10 = 0.5f * (tg[0] + tg[1] - tg[2] - tg[3]);
            float u11 = 0.5f * (tg[0] + tg[1] + tg[2] + tg[3]);
            *(float2*)(upp + (2 * h) * 64 + 2 * w)     = make_float2(u00, u01);
            *(float2*)(upp + (2 * h + 1) * 64 + 2 * w) = make_float2(u10, u11);
        }
    } else {
        // ---------------- role D: k_inproj (K-chunks of 16) ----------------
        int did = bid / 3;                 // 0..511
        int h0 = (did & 31) * 2;
        int b  = did >> 5;
        float* xs = smem;                  // 16*128 = 2048
        float* wt = smem + 2048;           // 16*128 = 2048, o-swizzled

        float acc[8][8];
#pragma unroll
        for (int i = 0; i < 8; ++i)
#pragma unroll
            for (int j = 0; j < 8; ++j) acc[i][j] = 0.f;

        int o0 = (tid >> 4) * 8;
        int p0 = (tid & 15) * 8;

        for (int ko = 0; ko < 64; ko += 16) {
            if (ko) __syncthreads();
            {
                int s = tid;
#pragma unroll
                for (int it = 0; it < 2; ++it, s += 256) {
                    int c = s >> 5, p4 = (s & 31) * 4;
                    float4 v = *(const float4*)(x + ((size_t)b * DIM + ko + c) * HW + h0 * 64 + p4);
                    *(float4*)(xs + c * 128 + p4) = v;
                }
            }
            {
                int s = tid;
#pragma unroll
                for (int it = 0; it < 2; ++it, s += 256) {
                    int o = s >> 2, c0 = (s & 3) * 4;
                    float4 v = *(const float4*)(in_w + o * 64 + ko + c0);
#pragma unroll
                    for (int i = 0; i < 4; ++i) {
                        int cc = c0 + i;
                        int osw = o ^ (((cc >> 2) & 3) << 3);
                        wt[cc * 128 + osw] = ((const float*)&v)[i];
                    }
                }
            }
            __syncthreads();
#pragma unroll 4
            for (int c = 0; c < 16; ++c) {
                int osw = o0 ^ (((c >> 2) & 3) << 3);
                float xv[8], wv[8];
                *(float4*)(xv)     = *(const float4*)(xs + c * 128 + p0);
                *(float4*)(xv + 4) = *(const float4*)(xs + c * 128 + p0 + 4);
                *(float4*)(wv)     = *(const float4*)(wt + c * 128 + osw);
                *(float4*)(wv + 4) = *(const float4*)(wt + c * 128 + osw + 4);
#pragma unroll
                for (int i = 0; i < 8; ++i)
#pragma unroll
                    for (int j = 0; j < 8; ++j)
                        acc[i][j] = fmaf(wv[i], xv[j], acc[i][j]);
            }
        }

#pragma unroll
        for (int i = 0; i < 8; ++i) {
            int o = o0 + i;
            float* dst = (o < 64) ? (xi + ((size_t)b * 64 + o) * HW + h0 * 64)
                                  : (z + ((size_t)b * 64 + (o - 64)) * HW + h0 * 64);
            *(float4*)(dst + p0)     = make_float4(acc[i][0], acc[i][1], acc[i][2], acc[i][3]);
            *(float4*)(dst + p0 + 4) = make_float4(acc[i][4], acc[i][5], acc[i][6], acc[i][7]);
        }
    }
}

// ===========================================================================
// STAGE 2: role E (blocks 0..511) = dwconv+silu -> xc + projections,
//          channel quarters of 16; role B (512..527) = expert-mixes
// ===========================================================================
__global__ __launch_bounds__(256) void k_stage2(
    const float* __restrict__ xi,
    const float* __restrict__ cw, const float* __restrict__ cb,
    const float* __restrict__ xpw,
    float* __restrict__ xc, float4* __restrict__ proj4, float2* __restrict__ projBC,
    const float* __restrict__ mean,
    const float* __restrict__ ew3, const float* __restrict__ gw3, const float* __restrict__ g13,
    const float* __restrict__ ew5, const float* __restrict__ gw5, const float* __restrict__ g15,
    const float* __restrict__ ew7, const float* __restrict__ gw7, const float* __restrict__ g17,
    float* __restrict__ w3o, float* __restrict__ w5o, float* __restrict__ w7o) {
    __shared__ float smem[6304];
    int bid = blockIdx.x;
    int tid = threadIdx.x;

    if (bid < 512) {
        // ---------------- role E: k_convproj, 16-channel quarters ----------------
        int h0 = (bid & 31) * 2;
        int b  = bid >> 5;
        float* xs  = smem;                 // 16*264 = 4224
        float* xcs = smem + 4224;          // 16*130 = 2080

        int dir = tid >> 7;
        int px  = tid & 127;
        float acc0 = 0.f, acc1 = 0.f, acc2 = 0.f, acc3 = 0.f, acc4 = 0.f, acc5 = 0.f;

        int cl_c = tid >> 4;               // 0..15 channel
        int p0_c = (tid & 15) * 8;         // 8 px within 128
        int row_c = p0_c >> 6;
        int wb_c  = p0_c & 63;

        for (int ch0 = 0; ch0 < 64; ch0 += 16) {
            if (ch0) __syncthreads();
            {
                int s = tid;
#pragma unroll
                for (int it = 0; it < 4; ++it, s += 256) {
                    int c = s >> 6;                  // 0..15
                    int rem = s & 63;
                    int r = rem >> 4, w4 = (rem & 15) * 4;
                    int gh = h0 - 1 + r;
                    float4 v = make_float4(0.f, 0.f, 0.f, 0.f);
                    if (gh >= 0 && gh < 64)
                        v = *(const float4*)(xi + ((size_t)b * 64 + ch0 + c) * HW + gh * 64 + w4);
                    float* dp = xs + c * 264 + r * 66 + 1 + w4;
                    dp[0] = v.x; dp[1] = v.y; dp[2] = v.z; dp[3] = v.w;
                }
                if (tid < 64) {
                    int cl = tid >> 2, r = tid & 3;
                    xs[cl * 264 + r * 66 + 0]  = 0.f;
                    xs[cl * 264 + r * 66 + 65] = 0.f;
                }
            }
            __syncthreads();

            {
                float wk[9];
#pragma unroll
                for (int j = 0; j < 9; ++j) wk[j] = cw[(ch0 + cl_c) * 9 + j];
                float bias = cb[ch0 + cl_c];
                float accr[8];
#pragma unroll
                for (int k = 0; k < 8; ++k) accr[k] = bias;
#pragma unroll
                for (int dy = 0; dy < 3; ++dy) {
                    const float* rp = xs + cl_c * 264 + (row_c + dy) * 66 + wb_c;
                    float r[10];
#pragma unroll
                    for (int q = 0; q < 10; ++q) r[q] = rp[q];
#pragma unroll
                    for (int k = 0; k < 8; ++k)
#pragma unroll
                        for (int dx = 0; dx < 3; ++dx)
                            accr[k] = fmaf(r[k + dx], wk[dy * 3 + dx], accr[k]);
                }
#pragma unroll
                for (int k = 0; k < 8; ++k)
                    xcs[cl_c * 130 + p0_c + k] = silu_f(accr[k]);
            }
            __syncthreads();

            {
                int s = tid;
#pragma unroll
                for (int it = 0; it < 2; ++it, s += 256) {
                    int c = s >> 5, pq = (s & 31) * 4;
                    const float* sp = xcs + c * 130 + pq;
                    *(float4*)(xc + ((size_t)b * 64 + ch0 + c) * HW + h0 * 64 + pq) =
                        make_float4(sp[0], sp[1], sp[2], sp[3]);
                }
            }
            {
                const float* wp = xpw + dir * 6 * 64 + ch0;
#pragma unroll 8
                for (int c = 0; c < 16; ++c) {
                    float xv = xcs[c * 130 + px];
                    acc0 = fmaf(xv, wp[0 * 64 + c], acc0);
                    acc1 = fmaf(xv, wp[1 * 64 + c], acc1);
                    acc2 = fmaf(xv, wp[2 * 64 + c], acc2);
                    acc3 = fmaf(xv, wp[3 * 64 + c], acc3);
                    acc4 = fmaf(xv, wp[4 * 64 + c], acc4);
                    acc5 = fmaf(xv, wp[5 * 64 + c], acc5);
                }
            }
        }

        int h = h0 + (px >> 6), w = px & 63;
        int l = (dir == 0) ? (h * 64 + w) : (w * 64 + h);
        size_t base = ((size_t)dir * NB + b) * HW + l;
        proj4[base]  = make_float4(acc0, acc1, acc2, acc3);
        projBC[base] = make_float2(acc4, acc5);
    } else {
        // ---------------- role B: k_weff_all ----------------
        int b = bid - 512;
        int c = tid;
        float* m = smem;
        float* g = smem + 64;
        if (c < 64) m[c] = mean[b * 64 + c];
        __syncthreads();
        const float rs = rsqrtf(1.f + 1e-5f);

#define WEFF_SECT(GW, EW, G1, OUT, K2)                                        \
        {                                                                     \
            if (c < 4) {                                                      \
                float l = 0.f;                                                \
                for (int cc = 0; cc < 64; ++cc) l += m[cc] * GW[c * 64 + cc]; \
                g[c] = l;                                                     \
            }                                                                 \
            __syncthreads();                                                  \
            if (c == 0) {                                                     \
                float mx = fmaxf(fmaxf(g[0], g[1]), fmaxf(g[2], g[3]));       \
                float e0 = expf(g[0] - mx), e1 = expf(g[1] - mx);             \
                float e2 = expf(g[2] - mx), e3 = expf(g[3] - mx);             \
                float inv = 1.f / (e0 + e1 + e2 + e3);                        \
                g[0] = e0 * inv; g[1] = e1 * inv; g[2] = e2 * inv; g[3] = e3 * inv; \
            }                                                                 \
            __syncthreads();                                                  \
            if (c < 64) {                                                     \
                float g1s = G1[c] * rs;                                       \
                for (int kk = 0; kk < K2; ++kk) {                             \
                    float w = 0.f;                                            \
                    for (int e = 0; e < 4; ++e) w += g[e] * EW[(e * 64 + c) * K2 + kk]; \
                    OUT[(b * 64 + c) * K2 + kk] = w * g1s;                    \
                }                                                             \
            }                                                                 \
            __syncthreads();                                                  \
        }

        WEFF_SECT(gw3, ew3, g13, w3o, 9)
        WEFF_SECT(gw5, ew5, g15, w5o, 25)
        WEFF_SECT(gw7, ew7, g17, w7o, 49)
#undef WEFF_SECT
    }
}

// ===========================================================================
// STAGE 3: selective scan, both directions per block (unchanged).
// ===========================================================================
__global__ __launch_bounds__(256) void k_scan2(const float* __restrict__ xc,
                                               const float4* __restrict__ proj4,
                                               const float2* __restrict__ projBC,
                                               const float* __restrict__ dt_w,
                                               const float* __restrict__ dt_b,
                                               const float* __restrict__ A_log,
                                               const float* __restrict__ Dp,
                                               const float* __restrict__ z,
                                               float* __restrict__ yz) {
    int wave = threadIdx.x >> 6;
    int lane = threadIdx.x & 63;
    int wid = blockIdx.x;                // b*64 + d
    int b = wid >> 6;
    int d = wid & 63;

    __shared__ float ut[64 * 65];
    __shared__ float al[4][1088];
    __shared__ float bl[4][1088];
    __shared__ float aggA[4], aggB[4];

    const float* uplane = xc + ((size_t)b * 64 + d) * HW;
    const float4* up4 = (const float4*)uplane;
#pragma unroll
    for (int q = 0; q < 4; ++q) {
        int s = q * 256 + threadIdx.x;
        float4 v = up4[s];
        int r = s >> 4, c0 = (s & 15) * 4;
        float* p = ut + r * 65 + c0;
        p[0] = v.x; p[1] = v.y; p[2] = v.z; p[3] = v.w;
    }
    __syncthreads();

    int ch = wave;
    float* a_my = al[wave];
    float* b_my = bl[wave];
    float y0r[16];

    // ================= DIR 0 =================
    {
        float4 wv = *(const float4*)(dt_w + d * 4);
        float db = dt_b[d];
        float A = -__expf(A_log[d]);
        float Dv = Dp[d];
        const float4* p4 = proj4 + (size_t)b * HW;
        const float2* pBC = projBC + (size_t)b * HW;

        float uv[16], cm[16];
#pragma unroll
        for (int j = 0; j < 16; ++j) {
            int el = j * 64 + lane;
            int e  = ch * 1024 + el;
            float4 t4 = p4[e];
            float2 t2 = pBC[e];
            float u = ut[(ch * 16 + j) * 65 + lane];
            uv[j] = u; cm[j] = t2.y;
            float pre = fmaf(t4.x, wv.x, fmaf(t4.y, wv.y,
                        fmaf(t4.z, wv.z, fmaf(t4.w, wv.w, db))));
            float delta = softplus_fast(pre);
            float aj = __expf(delta * A);
            float bj = delta * t2.x * u;
            int idx = (el >> 4) * 17 + (el & 15);
            a_my[idx] = aj;
            b_my[idx] = bj;
        }
        __builtin_amdgcn_wave_barrier();

        float a[16], bb[16];
#pragma unroll
        for (int j = 0; j < 16; ++j) {
            a[j]  = a_my[lane * 17 + j];
            bb[j] = b_my[lane * 17 + j];
        }
        float As = 1.f, Bs = 0.f;
#pragma unroll
        for (int j = 0; j < 16; ++j) { Bs = fmaf(a[j], Bs, bb[j]); As *= a[j]; }
        float Ai = As, Bi = Bs;
#pragma unroll
        for (int off = 1; off < 64; off <<= 1) {
            float ap = __shfl_up(Ai, (unsigned)off, 64);
            float bp = __shfl_up(Bi, (unsigned)off, 64);
            if (lane >= off) { Bi = fmaf(Ai, bp, Bi); Ai *= ap; }
        }
        if (lane == 63) { aggA[wave] = Ai; aggB[wave] = Bi; }
        __syncthreads();
        float carry = 0.f;
        for (int k = 0; k < wave; ++k) carry = fmaf(aggA[k], carry, aggB[k]);
        float ap1 = __shfl_up(Ai, 1, 64);
        float bp1 = __shfl_up(Bi, 1, 64);
        float h = (lane == 0) ? carry : fmaf(ap1, carry, bp1);
#pragma unroll
        for (int j = 0; j < 16; ++j) {
            h = fmaf(a[j], h, bb[j]);
            a_my[lane * 17 + j] = h;
        }
        __builtin_amdgcn_wave_barrier();
#pragma unroll
        for (int j = 0; j < 16; ++j) {
            int el = j * 64 + lane;
            float hv = a_my[(el >> 4) * 17 + (el & 15)];
            y0r[j] = fmaf(hv, cm[j], Dv * uv[j]);
        }
    }
    __syncthreads();

    // ================= DIR 1 =================
    {
        int pd = 64 + d;
        float4 wv = *(const float4*)(dt_w + pd * 4);
        float db = dt_b[pd];
        float A = -__expf(A_log[pd]);
        float Dv = Dp[pd];
        const float4* p4 = proj4 + ((size_t)NB + b) * HW;
        const float2* pBC = projBC + ((size_t)NB + b) * HW;

        float uv[16], cm[16];
#pragma unroll
        for (int j = 0; j < 16; ++j) {
            int el = j * 64 + lane;
            int e  = ch * 1024 + el;
            float4 t4 = p4[e];
            float2 t2 = pBC[e];
            float u = ut[lane * 65 + (ch * 16 + j)];
            uv[j] = u; cm[j] = t2.y;
            float pre = fmaf(t4.x, wv.x, fmaf(t4.y, wv.y,
                        fmaf(t4.z, wv.z, fmaf(t4.w, wv.w, db))));
            float delta = softplus_fast(pre);
            float aj = __expf(delta * A);
            float bj = delta * t2.x * u;
            int idx = (el >> 4) * 17 + (el & 15);
            a_my[idx] = aj;
            b_my[idx] = bj;
        }
        __builtin_amdgcn_wave_barrier();

        float a[16], bb[16];
#pragma unroll
        for (int j = 0; j < 16; ++j) {
            a[j]  = a_my[lane * 17 + j];
            bb[j] = b_my[lane * 17 + j];
        }
        float As = 1.f, Bs = 0.f;
#pragma unroll
        for (int j = 0; j < 16; ++j) { Bs = fmaf(a[j], Bs, bb[j]); As *= a[j]; }
        float Ai = As, Bi = Bs;
#pragma unroll
        for (int off = 1; off < 64; off <<= 1) {
            float ap = __shfl_up(Ai, (unsigned)off, 64);
            float bp = __shfl_up(Bi, (unsigned)off, 64);
            if (lane >= off) { Bi = fmaf(Ai, bp, Bi); Ai *= ap; }
        }
        if (lane == 63) { aggA[wave] = Ai; aggB[wave] = Bi; }
        __syncthreads();
        float carry = 0.f;
        for (int k = 0; k < wave; ++k) carry = fmaf(aggA[k], carry, aggB[k]);
        float ap1 = __shfl_up(Ai, 1, 64);
        float bp1 = __shfl_up(Bi, 1, 64);
        float h = (lane == 0) ? carry : fmaf(ap1, carry, bp1);
#pragma unroll
        for (int j = 0; j < 16; ++j) {
            h = fmaf(a[j], h, bb[j]);
            a_my[lane * 17 + j] = h;
        }
        __builtin_amdgcn_wave_barrier();
#pragma unroll
        for (int j = 0; j < 16; ++j) {
            int el = j * 64 + lane;
            float hv = a_my[(el >> 4) * 17 + (el & 15)];
            ut[lane * 65 + (ch * 16 + j)] = fmaf(hv, cm[j], Dv * uv[j]);
        }
    }
    __syncthreads();

    const float* zp = z + ((size_t)b * 64 + d) * HW;
    float* yp = yz + ((size_t)b * 64 + d) * HW;
#pragma unroll
    for (int j = 0; j < 16; ++j) {
        int e = ch * 1024 + j * 64 + lane;
        float y1v = ut[(ch * 16 + j) * 65 + lane];
        float zz = zp[e];
        yp[e] = (y0r[j] + y1v) * silu_f(zz);
    }
}

// ===========================================================================
// STAGE 4 (bid%9==8 -> G, else C)
//   role C = local conv + passthrough copy  (out channels [64:256])
//   role G = final GEMM, K-chunks of 16     (out channels [0:64])
// LDS union = 3072 floats (12.3KB).
// ===========================================================================
__global__ __launch_bounds__(256) void k_stage4(
    const float* __restrict__ x,
    const float* __restrict__ w3, const float* __restrict__ w5, const float* __restrict__ w7,
    const float* __restrict__ b1_0, const float* __restrict__ pw0,
    const float* __restrict__ g2_0, const float* __restrict__ b2_0,
    const float* __restrict__ b1_1, const float* __restrict__ pw1,
    const float* __restrict__ g2_1, const float* __restrict__ b2_1,
    const float* __restrict__ b1_2, const float* __restrict__ pw2,
    const float* __restrict__ g2_2, const float* __restrict__ b2_2,
    const float* __restrict__ yz, const float* __restrict__ ow,
    const float* __restrict__ base_scale, const float* __restrict__ up,
    float* __restrict__ out) {
    __shared__ float smem[3072];
    int bid = blockIdx.x;
    int tid = threadIdx.x;

    if (bid % 9 != 8) {
        // ---------------- role C: k_local + passthrough ----------------
        int cidx = (bid / 9) * 8 + (bid % 9);   // 0..4095
        int tile = cidx & 3;
        int c = (cidx >> 2) & 63;
        int b = cidx >> 8;
        int oy = (tile >> 1) * 32, ox = (tile & 1) * 32;
        float* t = smem;                   // 38*40 = 1520
        const float* xp = x + ((size_t)b * DIM + 64 + c) * HW;
        for (int i = tid; i < 38 * 38; i += 256) {
            int r = i / 38, cc = i % 38;
            int yy = r - 3 + oy, xx = cc - 3 + ox;
            t[r * 40 + cc] = (yy >= 0 && yy < 64 && xx >= 0 && xx < 64) ? xp[yy * 64 + xx] : 0.f;
        }
        // fused passthrough copy (hides under VALU-bound conv)
        {
            const float4* x4 = (const float4*)x;
            float4* o4 = (float4*)out;
            int base = cidx * 512;
#pragma unroll
            for (int it = 0; it < 2; ++it) {
                int idx = base + it * 256 + tid;
                int bb = idx >> 17;
                int r  = idx & 131071;
                int gi = bb * 262144 + 131072 + r;
                o4[gi] = x4[gi];
            }
        }
        const float* w3p = w3 + (b * 64 + c) * 9;
        const float* w5p = w5 + (b * 64 + c) * 25;
        const float* w7p = w7 + (b * 64 + c) * 49;
        float W3r[9], W5r[25], W7r[49];
#pragma unroll
        for (int j = 0; j < 9; ++j)  W3r[j] = w3p[j];
#pragma unroll
        for (int j = 0; j < 25; ++j) W5r[j] = w5p[j];
#pragma unroll
        for (int j = 0; j < 49; ++j) W7r[j] = w7p[j];
        __syncthreads();

        const float rs = rsqrtf(1.f + 1e-5f);
        float bb1a = b1_0[c], bb1b = b1_1[c], bb1c = b1_2[c];
        float ssa = pw0[c] * g2_0[c] * rs, ssb = pw1[c] * g2_1[c] * rs, ssc = pw2[c] * g2_2[c] * rs;
        float bb2a = b2_0[c], bb2b = b2_1[c], bb2c = b2_2[c];

        int y  = tid >> 3;
        int x0 = (tid & 7) * 4;

        float a3[4] = {0.f, 0.f, 0.f, 0.f};
        float a5[4] = {0.f, 0.f, 0.f, 0.f};
        float a7[4] = {0.f, 0.f, 0.f, 0.f};

#pragma unroll
        for (int dy = 0; dy < 7; ++dy) {
            const float4* rp = (const float4*)(t + (y + dy) * 40 + x0);
            float4 q0 = rp[0], q1 = rp[1], q2 = rp[2];
            float r[12] = {q0.x, q0.y, q0.z, q0.w, q1.x, q1.y, q1.z, q1.w,
                           q2.x, q2.y, q2.z, q2.w};
#pragma unroll
            for (int k = 0; k < 4; ++k)
#pragma unroll
                for (int dx = 0; dx < 7; ++dx)
                    a7[k] = fmaf(r[k + dx], W7r[dy * 7 + dx], a7[k]);
            if (dy >= 1 && dy <= 5) {
                int ey = dy - 1;
#pragma unroll
                for (int k = 0; k < 4; ++k)
#pragma unroll
                    for (int dx = 0; dx < 5; ++dx)
                        a5[k] = fmaf(r[k + 1 + dx], W5r[ey * 5 + dx], a5[k]);
            }
            if (dy >= 2 && dy <= 4) {
                int ey = dy - 2;
#pragma unroll
                for (int k = 0; k < 4; ++k)
#pragma unroll
                    for (int dx = 0; dx < 3; ++dx)
                        a3[k] = fmaf(r[k + 2 + dx], W3r[ey * 3 + dx], a3[k]);
            }
        }

        float4 res;
        float* rr = (float*)&res;
#pragma unroll
        for (int k = 0; k < 4; ++k) {
            rr[k] = mish_fast(a3[k] + bb1a) * ssa + bb2a
                  + mish_fast(a5[k] + bb1b) * ssb + bb2b
                  + mish_fast(a7[k] + bb1c) * ssc + bb2c;
        }
        float* op = out + ((size_t)b * DIM + 64 + c) * HW;
        *(float4*)(op + (oy + y) * 64 + ox + x0) = res;
    } else {
        // ---------------- role G: k_final (K-chunks of 16) ----------------
        int id2 = bid / 9;                 // 0..511
        int h0 = (id2 & 31) * 2;
        int b  = id2 >> 5;
        float* yv = smem;                  // 16*128 = 2048
        float* wt = smem + 2048;           // 16*64 = 1024, o-swizzled

        float acc[8][4];
#pragma unroll
        for (int i = 0; i < 8; ++i)
#pragma unroll
            for (int j = 0; j < 4; ++j) acc[i][j] = 0.f;

        int o0 = (tid >> 5) * 8;
        int p0 = (tid & 31) * 4;

        for (int ko = 0; ko < 64; ko += 16) {
            if (ko) __syncthreads();
            {
                int s = tid;
#pragma unroll
                for (int it = 0; it < 2; ++it, s += 256) {
                    int c = s >> 5, p4 = (s & 31) * 4;
                    size_t idx = ((size_t)b * 64 + ko + c) * HW + h0 * 64 + p4;
                    *(float4*)(yv + c * 128 + p4) = *(const float4*)(yz + idx);
                }
            }
            {
                int o = tid >> 2, c0 = (tid & 3) * 4;
                float4 v = *(const float4*)(ow + o * 64 + ko + c0);
#pragma unroll
                for (int i = 0; i < 4; ++i) {
                    int cc = c0 + i;
                    int osw = o ^ (((cc >> 2) & 3) << 3);
                    wt[cc * 64 + osw] = ((const float*)&v)[i];
                }
            }
            __syncthreads();
#pragma unroll 4
            for (int c = 0; c < 16; ++c) {
                int osw = o0 ^ (((c >> 2) & 3) << 3);
                float wv[8], xv[4];
                *(float4*)(wv)     = *(const float4*)(wt + c * 64 + osw);
                *(float4*)(wv + 4) = *(const float4*)(wt + c * 64 + osw + 4);
                *(float4*)(xv)     = *(const float4*)(yv + c * 128 + p0);
#pragma unroll
                for (int i = 0; i < 8; ++i)
#pragma unroll
                    for (int j = 0; j < 4; ++j)
                        acc[i][j] = fmaf(wv[i], xv[j], acc[i][j]);
            }
        }

#pragma unroll
        for (int i = 0; i < 8; ++i) {
            int o = o0 + i;
            float bs = base_scale[o];
            float4 u = *(const float4*)(up + ((size_t)b * 64 + o) * HW + h0 * 64 + p0);
            float4 r = make_float4(fmaf(bs, acc[i][0], u.x),
                                   fmaf(bs, acc[i][1], u.y),
                                   fmaf(bs, acc[i][2], u.z),
                                   fmaf(bs, acc[i][3], u.w));
            *(float4*)(out + ((size_t)b * DIM + o) * HW + h0 * 64 + p0) = r;
        }
    }
}

// ---------------------------------------------------------------------------
extern "C" void kernel_launch(void* const* d_in, const int* in_sizes, int n_in,
                              void* d_out, int out_size, void* d_ws, size_t ws_size,
                              hipStream_t stream) {
    (void)in_sizes; (void)n_in; (void)out_size; (void)ws_size;
    const float* x = (const float*)d_in[0];
    float* out = (float*)d_out;
    float* ws = (float*)d_ws;

    const size_t IMG = (size_t)NB * 64 * HW;   // 4,194,304 floats
    float* buf_xi   = ws;                      // xi, later reused as yz
    float* buf_z    = ws + IMG;
    float* buf_xc   = ws + 2 * IMG;
    float* buf_up   = ws + 3 * IMG;
    float* buf_p4   = ws + 4 * IMG;            // float4[2*16*4096]
    float* buf_pBC  = buf_p4 + (size_t)4 * 2 * NB * HW;
    float* buf_mean = buf_pBC + (size_t)2 * 2 * NB * HW;
    float* buf_w3   = buf_mean + 1024;
    float* buf_w5   = buf_w3 + 16 * 64 * 9;
    float* buf_w7   = buf_w5 + 16 * 64 * 25;

    // stage1: wavelet-up + mean (A) || input projection (D)
    k_stage1<<<1536, 256, 0, stream>>>(x,
        (const float*)d_in[22], (const float*)d_in[23], (const float*)d_in[24],
        buf_up, buf_mean,
        (const float*)d_in[26], buf_xi, buf_z);

    // stage2: dwconv+proj (E) || expert-mix weights (B)
    k_stage2<<<528, 256, 0, stream>>>(buf_xi,
        (const float*)d_in[27], (const float*)d_in[28], (const float*)d_in[29],
        buf_xc, (float4*)buf_p4, (float2*)buf_pBC,
        buf_mean,
        (const float*)d_in[1],  (const float*)d_in[2],  (const float*)d_in[3],
        (const float*)d_in[8],  (const float*)d_in[9],  (const float*)d_in[10],
        (const float*)d_in[15], (const float*)d_in[16], (const float*)d_in[17],
        buf_w3, buf_w5, buf_w7);

    // stage3: dual-direction selective scan -> yz (xi is dead, reuse)
    k_scan2<<<1024, 256, 0, stream>>>(buf_xc, (const float4*)buf_p4, (const float2*)buf_pBC,
        (const float*)d_in[30], (const float*)d_in[31],
        (const float*)d_in[32], (const float*)d_in[33],
        buf_z, buf_xi);

    // stage4: local conv + passthrough (C) || final GEMM (G), interleaved
    k_stage4<<<4608, 256, 0, stream>>>(x, buf_w3, buf_w5, buf_w7,
        (const float*)d_in[4],  (const float*)d_in[5],  (const float*)d_in[6],  (const float*)d_in[7],
        (const float*)d_in[11], (const float*)d_in[12], (const float*)d_in[13], (const float*)d_in[14],
        (const float*)d_in[18], (const float*)d_in[19], (const float*)d_in[20], (const float*)d_in[21],
        buf_xi, (const float*)d_in[34], (const float*)d_in[25], buf_up, out);
}

// Round 16
// 118.062 us; speedup vs baseline: 1.0181x; 1.0181x over previous
//
#include <hip/hip_runtime.h>
#include <math.h>

// Problem constants
static constexpr int NB   = 16;    // batch
static constexpr int DIM  = 256;   // total channels
static constexpr int CG   = 64;    // global-branch channels
static constexpr int HH   = 64;
static constexpr int WW   = 64;
static constexpr int HW   = HH * WW;   // 4096

// mish(x) = x*tanh(softplus(x)) = x*(t^2+2t)/(t^2+2t+2), t=e^x.
__device__ __forceinline__ float mish_fast(float x) {
    float t = __expf(fminf(x, 20.f));
    float p = __builtin_fmaf(t, t, t + t);         // t^2 + 2t
    return x * p * __builtin_amdgcn_rcpf(p + 2.f);
}
__device__ __forceinline__ float silu_f(float x) {
    return x * __builtin_amdgcn_rcpf(1.f + __expf(-x));
}
__device__ __forceinline__ float softplus_fast(float x) {
    return fmaxf(x, 0.f) + __logf(1.f + __expf(-fabsf(x)));
}

// ===========================================================================
// STAGE 1 (roles interleaved: bid%3==2 -> D, else A)
//   role A = wavelet up (register-direct Haar dec) + channel mean (wave-reduce)
//   role D = ss2d input projection GEMM (wt o-index XOR-swizzled, b128-safe)
// ===========================================================================
__global__ __launch_bounds__(256) void k_stage1(
    const float* __restrict__ x,
    const float* __restrict__ wav_w, const float* __restrict__ wav_b,
    const float* __restrict__ wav_scale,
    float* __restrict__ up, float* __restrict__ mean,
    const float* __restrict__ in_w,
    float* __restrict__ xi, float* __restrict__ z) {
    __shared__ float smem[8192];
    int bid = blockIdx.x;
    int tid = threadIdx.x;

    if (bid % 3 != 2) {
        // ---------------- role A: wavelet + mean ----------------
        int aid = (bid / 3) * 2 + (bid % 3);   // 0..1023
        int c = aid & 63, b = aid >> 6;
        float* wtb = smem;                 // 4 planes * (32*34) = 4352
        float* red = smem + 4352;          // 4
        const float* xp = x + ((size_t)b * DIM + c) * HW;

        // mean of plane (b, 64+c): float4 loads + wave shuffle reduce (2 barriers)
        {
            const float4* lp4 = (const float4*)(x + ((size_t)b * DIM + 64 + c) * HW);
            float s = 0.f;
            for (int i = tid; i < 1024; i += 256) {
                float4 v = lp4[i];
                s += (v.x + v.y) + (v.z + v.w);
            }
#pragma unroll
            for (int off = 32; off > 0; off >>= 1) s += __shfl_xor(s, off, 64);
            if ((tid & 63) == 0) red[tid >> 6] = s;
            __syncthreads();
            if (tid == 0)
                mean[b * 64 + c] = ((red[0] + red[1]) + (red[2] + red[3])) * (1.f / HW);
        }

        // register-direct Haar dec
#pragma unroll
        for (int it = 0; it < 2; ++it) {
            int p = tid + it * 256;        // 0..511
            int h = p >> 4, w2 = p & 15;
            float4 top = *(const float4*)(xp + (2 * h) * 64 + 4 * w2);
            float4 bot = *(const float4*)(xp + (2 * h + 1) * 64 + 4 * w2);
            float a0 = top.x, b0 = top.y, c0q = bot.x, d0 = bot.y;
            float a1 = top.z, b1 = top.w, c1q = bot.z, d1 = bot.w;
            int base0 = h * 34 + 2 * w2;
            *(float2*)(wtb + 0 * 1088 + base0) =
                make_float2(0.5f * (a0 + b0 + c0q + d0), 0.5f * (a1 + b1 + c1q + d1));
            *(float2*)(wtb + 1 * 1088 + base0) =
                make_float2(0.5f * (a0 + b0 - c0q - d0), 0.5f * (a1 + b1 - c1q - d1));
            *(float2*)(wtb + 2 * 1088 + base0) =
                make_float2(0.5f * (a0 - b0 + c0q - d0), 0.5f * (a1 - b1 + c1q - d1));
            *(float2*)(wtb + 3 * 1088 + base0) =
                make_float2(0.5f * (a0 - b0 - c0q + d0), 0.5f * (a1 - b1 - c1q + d1));
        }
        __syncthreads();

        float wk[4][9], tb[4];
#pragma unroll
        for (int k = 0; k < 4; ++k) {
            int ch = c * 4 + k;
            float sc = wav_scale[ch];
#pragma unroll
            for (int j = 0; j < 9; ++j) wk[k][j] = wav_w[ch * 9 + j] * sc;
            tb[k] = wav_b[ch] * sc;
        }
        float* upp = up + ((size_t)b * CG + c) * HW;
        for (int i = tid; i < 1024; i += 256) {
            int h = i >> 5, w = i & 31;
            float tg[4];
#pragma unroll
            for (int k = 0; k < 4; ++k) {
                float s = tb[k];
#pragma unroll
                for (int dy = -1; dy <= 1; ++dy) {
                    int hh = h + dy;
                    if (hh < 0 || hh >= 32) continue;
#pragma unroll
                    for (int dx = -1; dx <= 1; ++dx) {
                        int wx = w + dx;
                        if (wx < 0 || wx >= 32) continue;
                        s = fmaf(wtb[k * 1088 + hh * 34 + wx], wk[k][(dy + 1) * 3 + (dx + 1)], s);
                    }
                }
                tg[k] = s;
            }
            float u00 = 0.5f * (tg[0] - tg[1] - tg[2] + tg[3]);
            float u01 = 0.5f * (tg[0] - tg[1] + tg[2] - tg[3]);
            float u10 = 0.5f * (tg[0] + tg[1] - tg[2] - tg[3]);
            float u11 = 0.5f * (tg[0] + tg[1] + tg[2] + tg[3]);
            *(float2*)(upp + (2 * h) * 64 + 2 * w)     = make_float2(u00, u01);
            *(float2*)(upp + (2 * h + 1) * 64 + 2 * w) = make_float2(u10, u11);
        }
    } else {
        // ---------------- role D: k_inproj ----------------
        int id2 = bid / 3;                 // 0..511
        int h0 = (id2 & 31) * 2;
        int b  = id2 >> 5;
        float* xs = smem;                  // 32*128
        float* wt = smem + 4096;           // 32*128, o-index swizzled

        float acc[8][8];
#pragma unroll
        for (int i = 0; i < 8; ++i)
#pragma unroll
            for (int j = 0; j < 8; ++j) acc[i][j] = 0.f;

        int o0 = (tid >> 4) * 8;
        int p0 = (tid & 15) * 8;

        for (int ko = 0; ko < 64; ko += 32) {
            if (ko) __syncthreads();
            {
                int s = tid;
#pragma unroll
                for (int it = 0; it < 4; ++it, s += 256) {
                    int c = s >> 5, p4 = (s & 31) * 4;
                    float4 v = *(const float4*)(x + ((size_t)b * DIM + ko + c) * HW + h0 * 64 + p4);
                    *(float4*)(xs + c * 128 + p4) = v;
                }
            }
            {
                int s = tid;
#pragma unroll
                for (int it = 0; it < 4; ++it, s += 256) {
                    int o = s >> 3, c0 = (s & 7) * 4;
#pragma unroll
                    for (int i = 0; i < 4; ++i) {
                        int cc = c0 + i;
                        int osw = o ^ (((cc >> 2) & 3) << 3);   // bank spread, b128-safe
                        wt[cc * 128 + osw] = ((const float*)(in_w + o * 64 + ko + c0))[i];
                    }
                }
            }
            __syncthreads();
#pragma unroll 4
            for (int c = 0; c < 32; ++c) {
                int osw = o0 ^ (((c >> 2) & 3) << 3);
                float xv[8], wv[8];
                *(float4*)(xv)     = *(const float4*)(xs + c * 128 + p0);
                *(float4*)(xv + 4) = *(const float4*)(xs + c * 128 + p0 + 4);
                *(float4*)(wv)     = *(const float4*)(wt + c * 128 + osw);
                *(float4*)(wv + 4) = *(const float4*)(wt + c * 128 + osw + 4);
#pragma unroll
                for (int i = 0; i < 8; ++i)
#pragma unroll
                    for (int j = 0; j < 8; ++j)
                        acc[i][j] = fmaf(wv[i], xv[j], acc[i][j]);
            }
        }

#pragma unroll
        for (int i = 0; i < 8; ++i) {
            int o = o0 + i;
            float* dst = (o < 64) ? (xi + ((size_t)b * 64 + o) * HW + h0 * 64)
                                  : (z + ((size_t)b * 64 + (o - 64)) * HW + h0 * 64);
            *(float4*)(dst + p0)     = make_float4(acc[i][0], acc[i][1], acc[i][2], acc[i][3]);
            *(float4*)(dst + p0 + 4) = make_float4(acc[i][4], acc[i][5], acc[i][6], acc[i][7]);
        }
    }
}

// ===========================================================================
// STAGE 2: role E (blocks 0..511) = fused dwconv+silu -> xc, projections
//          role B (blocks 512..527) = all three expert-mixes
// ===========================================================================
__global__ __launch_bounds__(256) void k_stage2(
    const float* __restrict__ xi,
    const float* __restrict__ cw, const float* __restrict__ cb,
    const float* __restrict__ xpw,
    float* __restrict__ xc, float4* __restrict__ proj4, float2* __restrict__ projBC,
    const float* __restrict__ mean,
    const float* __restrict__ ew3, const float* __restrict__ gw3, const float* __restrict__ g13,
    const float* __restrict__ ew5, const float* __restrict__ gw5, const float* __restrict__ g15,
    const float* __restrict__ ew7, const float* __restrict__ gw7, const float* __restrict__ g17,
    float* __restrict__ w3o, float* __restrict__ w5o, float* __restrict__ w7o) {
    __shared__ float smem[12608];
    int bid = blockIdx.x;
    int tid = threadIdx.x;

    if (bid < 512) {
        // ---------------- role E: k_convproj ----------------
        int h0 = (bid & 31) * 2;
        int b  = bid >> 5;
        float* xs  = smem;                 // 32*264 = 8448
        float* xcs = smem + 8448;          // 32*130 = 4160

        int dir = tid >> 7;
        int px  = tid & 127;
        float acc0 = 0.f, acc1 = 0.f, acc2 = 0.f, acc3 = 0.f, acc4 = 0.f, acc5 = 0.f;

        int cl_c = tid >> 3;
        int p0_c = (tid & 7) * 16;
        int row_c = p0_c >> 6;
        int wb_c  = p0_c & 63;

        for (int ch0 = 0; ch0 < 64; ch0 += 32) {
            if (ch0) __syncthreads();
            {
                int s = tid;
#pragma unroll
                for (int it = 0; it < 8; ++it, s += 256) {
                    int c = s >> 6;
                    int rem = s & 63;
                    int r = rem >> 4, w4 = (rem & 15) * 4;
                    int gh = h0 - 1 + r;
                    float4 v = make_float4(0.f, 0.f, 0.f, 0.f);
                    if (gh >= 0 && gh < 64)
                        v = *(const float4*)(xi + ((size_t)b * 64 + ch0 + c) * HW + gh * 64 + w4);
                    float* dp = xs + c * 264 + r * 66 + 1 + w4;
                    dp[0] = v.x; dp[1] = v.y; dp[2] = v.z; dp[3] = v.w;
                }
                if (tid < 128) {
                    int cl = tid >> 2, r = tid & 3;
                    xs[cl * 264 + r * 66 + 0]  = 0.f;
                    xs[cl * 264 + r * 66 + 65] = 0.f;
                }
            }
            __syncthreads();

            {
                float wk[9];
#pragma unroll
                for (int j = 0; j < 9; ++j) wk[j] = cw[(ch0 + cl_c) * 9 + j];
                float bias = cb[ch0 + cl_c];
                float accr[16];
#pragma unroll
                for (int k = 0; k < 16; ++k) accr[k] = bias;
#pragma unroll
                for (int dy = 0; dy < 3; ++dy) {
                    const float* rp = xs + cl_c * 264 + (row_c + dy) * 66 + wb_c;
                    float r[18];
#pragma unroll
                    for (int q = 0; q < 18; ++q) r[q] = rp[q];
#pragma unroll
                    for (int k = 0; k < 16; ++k)
#pragma unroll
                        for (int dx = 0; dx < 3; ++dx)
                            accr[k] = fmaf(r[k + dx], wk[dy * 3 + dx], accr[k]);
                }
#pragma unroll
                for (int k = 0; k < 16; ++k)
                    xcs[cl_c * 130 + p0_c + k] = silu_f(accr[k]);
            }
            __syncthreads();

            {
                int s = tid;
#pragma unroll
                for (int it = 0; it < 4; ++it, s += 256) {
                    int c = s >> 5, pq = (s & 31) * 4;
                    const float* sp = xcs + c * 130 + pq;
                    *(float4*)(xc + ((size_t)b * 64 + ch0 + c) * HW + h0 * 64 + pq) =
                        make_float4(sp[0], sp[1], sp[2], sp[3]);
                }
            }
            {
                const float* wp = xpw + dir * 6 * 64 + ch0;
#pragma unroll 8
                for (int c = 0; c < 32; ++c) {
                    float xv = xcs[c * 130 + px];
                    acc0 = fmaf(xv, wp[0 * 64 + c], acc0);
                    acc1 = fmaf(xv, wp[1 * 64 + c], acc1);
                    acc2 = fmaf(xv, wp[2 * 64 + c], acc2);
                    acc3 = fmaf(xv, wp[3 * 64 + c], acc3);
                    acc4 = fmaf(xv, wp[4 * 64 + c], acc4);
                    acc5 = fmaf(xv, wp[5 * 64 + c], acc5);
                }
            }
        }

        int h = h0 + (px >> 6), w = px & 63;
        int l = (dir == 0) ? (h * 64 + w) : (w * 64 + h);
        size_t base = ((size_t)dir * NB + b) * HW + l;
        proj4[base]  = make_float4(acc0, acc1, acc2, acc3);
        projBC[base] = make_float2(acc4, acc5);
    } else {
        // ---------------- role B: k_weff_all ----------------
        int b = bid - 512;
        int c = tid;
        float* m = smem;
        float* g = smem + 64;
        if (c < 64) m[c] = mean[b * 64 + c];
        __syncthreads();
        const float rs = rsqrtf(1.f + 1e-5f);

#define WEFF_SECT(GW, EW, G1, OUT, K2)                                        \
        {                                                                     \
            if (c < 4) {                                                      \
                float l = 0.f;                                                \
                for (int cc = 0; cc < 64; ++cc) l += m[cc] * GW[c * 64 + cc]; \
                g[c] = l;                                                     \
            }                                                                 \
            __syncthreads();                                                  \
            if (c == 0) {                                                     \
                float mx = fmaxf(fmaxf(g[0], g[1]), fmaxf(g[2], g[3]));       \
                float e0 = expf(g[0] - mx), e1 = expf(g[1] - mx);             \
                float e2 = expf(g[2] - mx), e3 = expf(g[3] - mx);             \
                float inv = 1.f / (e0 + e1 + e2 + e3);                        \
                g[0] = e0 * inv; g[1] = e1 * inv; g[2] = e2 * inv; g[3] = e3 * inv; \
            }                                                                 \
            __syncthreads();                                                  \
            if (c < 64) {                                                     \
                float g1s = G1[c] * rs;                                       \
                for (int kk = 0; kk < K2; ++kk) {                             \
                    float w = 0.f;                                            \
                    for (int e = 0; e < 4; ++e) w += g[e] * EW[(e * 64 + c) * K2 + kk]; \
                    OUT[(b * 64 + c) * K2 + kk] = w * g1s;                    \
                }                                                             \
            }                                                                 \
            __syncthreads();                                                  \
        }

        WEFF_SECT(gw3, ew3, g13, w3o, 9)
        WEFF_SECT(gw5, ew5, g15, w5o, 25)
        WEFF_SECT(gw7, ew7, g17, w7o, 49)
#undef WEFF_SECT
    }
}

// ===========================================================================
// STAGE 3: selective scan, both directions per block (unchanged).
// ===========================================================================
__global__ __launch_bounds__(256) void k_scan2(const float* __restrict__ xc,
                                               const float4* __restrict__ proj4,
                                               const float2* __restrict__ projBC,
                                               const float* __restrict__ dt_w,
                                               const float* __restrict__ dt_b,
                                               const float* __restrict__ A_log,
                                               const float* __restrict__ Dp,
                                               const float* __restrict__ z,
                                               float* __restrict__ yz) {
    int wave = threadIdx.x >> 6;
    int lane = threadIdx.x & 63;
    int wid = blockIdx.x;                // b*64 + d
    int b = wid >> 6;
    int d = wid & 63;

    __shared__ float ut[64 * 65];
    __shared__ float al[4][1088];
    __shared__ float bl[4][1088];
    __shared__ float aggA[4], aggB[4];

    const float* uplane = xc + ((size_t)b * 64 + d) * HW;
    const float4* up4 = (const float4*)uplane;
#pragma unroll
    for (int q = 0; q < 4; ++q) {
        int s = q * 256 + threadIdx.x;
        float4 v = up4[s];
        int r = s >> 4, c0 = (s & 15) * 4;
        float* p = ut + r * 65 + c0;
        p[0] = v.x; p[1] = v.y; p[2] = v.z; p[3] = v.w;
    }
    __syncthreads();

    int ch = wave;
    float* a_my = al[wave];
    float* b_my = bl[wave];
    float y0r[16];

    // ================= DIR 0 =================
    {
        float4 wv = *(const float4*)(dt_w + d * 4);
        float db = dt_b[d];
        float A = -__expf(A_log[d]);
        float Dv = Dp[d];
        const float4* p4 = proj4 + (size_t)b * HW;
        const float2* pBC = projBC + (size_t)b * HW;

        float uv[16], cm[16];
#pragma unroll
        for (int j = 0; j < 16; ++j) {
            int el = j * 64 + lane;
            int e  = ch * 1024 + el;
            float4 t4 = p4[e];
            float2 t2 = pBC[e];
            float u = ut[(ch * 16 + j) * 65 + lane];
            uv[j] = u; cm[j] = t2.y;
            float pre = fmaf(t4.x, wv.x, fmaf(t4.y, wv.y,
                        fmaf(t4.z, wv.z, fmaf(t4.w, wv.w, db))));
            float delta = softplus_fast(pre);
            float aj = __expf(delta * A);
            float bj = delta * t2.x * u;
            int idx = (el >> 4) * 17 + (el & 15);
            a_my[idx] = aj;
            b_my[idx] = bj;
        }
        __builtin_amdgcn_wave_barrier();

        float a[16], bb[16];
#pragma unroll
        for (int j = 0; j < 16; ++j) {
            a[j]  = a_my[lane * 17 + j];
            bb[j] = b_my[lane * 17 + j];
        }
        float As = 1.f, Bs = 0.f;
#pragma unroll
        for (int j = 0; j < 16; ++j) { Bs = fmaf(a[j], Bs, bb[j]); As *= a[j]; }
        float Ai = As, Bi = Bs;
#pragma unroll
        for (int off = 1; off < 64; off <<= 1) {
            float ap = __shfl_up(Ai, (unsigned)off, 64);
            float bp = __shfl_up(Bi, (unsigned)off, 64);
            if (lane >= off) { Bi = fmaf(Ai, bp, Bi); Ai *= ap; }
        }
        if (lane == 63) { aggA[wave] = Ai; aggB[wave] = Bi; }
        __syncthreads();
        float carry = 0.f;
        for (int k = 0; k < wave; ++k) carry = fmaf(aggA[k], carry, aggB[k]);
        float ap1 = __shfl_up(Ai, 1, 64);
        float bp1 = __shfl_up(Bi, 1, 64);
        float h = (lane == 0) ? carry : fmaf(ap1, carry, bp1);
#pragma unroll
        for (int j = 0; j < 16; ++j) {
            h = fmaf(a[j], h, bb[j]);
            a_my[lane * 17 + j] = h;
        }
        __builtin_amdgcn_wave_barrier();
#pragma unroll
        for (int j = 0; j < 16; ++j) {
            int el = j * 64 + lane;
            float hv = a_my[(el >> 4) * 17 + (el & 15)];
            y0r[j] = fmaf(hv, cm[j], Dv * uv[j]);
        }
    }
    __syncthreads();

    // ================= DIR 1 =================
    {
        int pd = 64 + d;
        float4 wv = *(const float4*)(dt_w + pd * 4);
        float db = dt_b[pd];
        float A = -__expf(A_log[pd]);
        float Dv = Dp[pd];
        const float4* p4 = proj4 + ((size_t)NB + b) * HW;
        const float2* pBC = projBC + ((size_t)NB + b) * HW;

        float uv[16], cm[16];
#pragma unroll
        for (int j = 0; j < 16; ++j) {
            int el = j * 64 + lane;
            int e  = ch * 1024 + el;
            float4 t4 = p4[e];
            float2 t2 = pBC[e];
            float u = ut[lane * 65 + (ch * 16 + j)];
            uv[j] = u; cm[j] = t2.y;
            float pre = fmaf(t4.x, wv.x, fmaf(t4.y, wv.y,
                        fmaf(t4.z, wv.z, fmaf(t4.w, wv.w, db))));
            float delta = softplus_fast(pre);
            float aj = __expf(delta * A);
            float bj = delta * t2.x * u;
            int idx = (el >> 4) * 17 + (el & 15);
            a_my[idx] = aj;
            b_my[idx] = bj;
        }
        __builtin_amdgcn_wave_barrier();

        float a[16], bb[16];
#pragma unroll
        for (int j = 0; j < 16; ++j) {
            a[j]  = a_my[lane * 17 + j];
            bb[j] = b_my[lane * 17 + j];
        }
        float As = 1.f, Bs = 0.f;
#pragma unroll
        for (int j = 0; j < 16; ++j) { Bs = fmaf(a[j], Bs, bb[j]); As *= a[j]; }
        float Ai = As, Bi = Bs;
#pragma unroll
        for (int off = 1; off < 64; off <<= 1) {
            float ap = __shfl_up(Ai, (unsigned)off, 64);
            float bp = __shfl_up(Bi, (unsigned)off, 64);
            if (lane >= off) { Bi = fmaf(Ai, bp, Bi); Ai *= ap; }
        }
        if (lane == 63) { aggA[wave] = Ai; aggB[wave] = Bi; }
        __syncthreads();
        float carry = 0.f;
        for (int k = 0; k < wave; ++k) carry = fmaf(aggA[k], carry, aggB[k]);
        float ap1 = __shfl_up(Ai, 1, 64);
        float bp1 = __shfl_up(Bi, 1, 64);
        float h = (lane == 0) ? carry : fmaf(ap1, carry, bp1);
#pragma unroll
        for (int j = 0; j < 16; ++j) {
            h = fmaf(a[j], h, bb[j]);
            a_my[lane * 17 + j] = h;
        }
        __builtin_amdgcn_wave_barrier();
#pragma unroll
        for (int j = 0; j < 16; ++j) {
            int el = j * 64 + lane;
            float hv = a_my[(el >> 4) * 17 + (el & 15)];
            ut[lane * 65 + (ch * 16 + j)] = fmaf(hv, cm[j], Dv * uv[j]);
        }
    }
    __syncthreads();

    const float* zp = z + ((size_t)b * 64 + d) * HW;
    float* yp = yz + ((size_t)b * 64 + d) * HW;
#pragma unroll
    for (int j = 0; j < 16; ++j) {
        int e = ch * 1024 + j * 64 + lane;
        float y1v = ut[(ch * 16 + j) * 65 + lane];
        float zz = zp[e];
        yp[e] = (y0r[j] + y1v) * silu_f(zz);
    }
}

// ===========================================================================
// STAGE 4 (roles interleaved: bid%9==8 -> G, else C)
//   role C = local conv + passthrough copy  (out channels [64:256])
//   role G = final GEMM (wt o-index XOR-swizzled) + up add (out [0:64])
// ===========================================================================
__global__ __launch_bounds__(256) void k_stage4(
    const float* __restrict__ x,
    const float* __restrict__ w3, const float* __restrict__ w5, const float* __restrict__ w7,
    const float* __restrict__ b1_0, const float* __restrict__ pw0,
    const float* __restrict__ g2_0, const float* __restrict__ b2_0,
    const float* __restrict__ b1_1, const float* __restrict__ pw1,
    const float* __restrict__ g2_1, const float* __restrict__ b2_1,
    const float* __restrict__ b1_2, const float* __restrict__ pw2,
    const float* __restrict__ g2_2, const float* __restrict__ b2_2,
    const float* __restrict__ yz, const float* __restrict__ ow,
    const float* __restrict__ base_scale, const float* __restrict__ up,
    float* __restrict__ out) {
    __shared__ float smem[6144];
    int bid = blockIdx.x;
    int tid = threadIdx.x;

    if (bid % 9 != 8) {
        // ---------------- role C: k_local + passthrough ----------------
        int cidx = (bid / 9) * 8 + (bid % 9);   // 0..4095
        int tile = cidx & 3;
        int c = (cidx >> 2) & 63;
        int b = cidx >> 8;
        int oy = (tile >> 1) * 32, ox = (tile & 1) * 32;
        float* t = smem;                   // 38*40 = 1520
        const float* xp = x + ((size_t)b * DIM + 64 + c) * HW;
        for (int i = tid; i < 38 * 38; i += 256) {
            int r = i / 38, cc = i % 38;
            int yy = r - 3 + oy, xx = cc - 3 + ox;
            t[r * 40 + cc] = (yy >= 0 && yy < 64 && xx >= 0 && xx < 64) ? xp[yy * 64 + xx] : 0.f;
        }
        // fused passthrough copy
        {
            const float4* x4 = (const float4*)x;
            float4* o4 = (float4*)out;
            int base = cidx * 512;
#pragma unroll
            for (int it = 0; it < 2; ++it) {
                int idx = base + it * 256 + tid;
                int bb = idx >> 17;
                int r  = idx & 131071;
                int gi = bb * 262144 + 131072 + r;
                o4[gi] = x4[gi];
            }
        }
        const float* w3p = w3 + (b * 64 + c) * 9;
        const float* w5p = w5 + (b * 64 + c) * 25;
        const float* w7p = w7 + (b * 64 + c) * 49;
        float W3r[9], W5r[25], W7r[49];
#pragma unroll
        for (int j = 0; j < 9; ++j)  W3r[j] = w3p[j];
#pragma unroll
        for (int j = 0; j < 25; ++j) W5r[j] = w5p[j];
#pragma unroll
        for (int j = 0; j < 49; ++j) W7r[j] = w7p[j];
        __syncthreads();

        const float rs = rsqrtf(1.f + 1e-5f);
        float bb1a = b1_0[c], bb1b = b1_1[c], bb1c = b1_2[c];
        float ssa = pw0[c] * g2_0[c] * rs, ssb = pw1[c] * g2_1[c] * rs, ssc = pw2[c] * g2_2[c] * rs;
        float bb2a = b2_0[c], bb2b = b2_1[c], bb2c = b2_2[c];

        int y  = tid >> 3;
        int x0 = (tid & 7) * 4;

        float a3[4] = {0.f, 0.f, 0.f, 0.f};
        float a5[4] = {0.f, 0.f, 0.f, 0.f};
        float a7[4] = {0.f, 0.f, 0.f, 0.f};

#pragma unroll
        for (int dy = 0; dy < 7; ++dy) {
            const float4* rp = (const float4*)(t + (y + dy) * 40 + x0);
            float4 q0 = rp[0], q1 = rp[1], q2 = rp[2];
            float r[12] = {q0.x, q0.y, q0.z, q0.w, q1.x, q1.y, q1.z, q1.w,
                           q2.x, q2.y, q2.z, q2.w};
#pragma unroll
            for (int k = 0; k < 4; ++k)
#pragma unroll
                for (int dx = 0; dx < 7; ++dx)
                    a7[k] = fmaf(r[k + dx], W7r[dy * 7 + dx], a7[k]);
            if (dy >= 1 && dy <= 5) {
                int ey = dy - 1;
#pragma unroll
                for (int k = 0; k < 4; ++k)
#pragma unroll
                    for (int dx = 0; dx < 5; ++dx)
                        a5[k] = fmaf(r[k + 1 + dx], W5r[ey * 5 + dx], a5[k]);
            }
            if (dy >= 2 && dy <= 4) {
                int ey = dy - 2;
#pragma unroll
                for (int k = 0; k < 4; ++k)
#pragma unroll
                    for (int dx = 0; dx < 3; ++dx)
                        a3[k] = fmaf(r[k + 2 + dx], W3r[ey * 3 + dx], a3[k]);
            }
        }

        float4 res;
        float* rr = (float*)&res;
#pragma unroll
        for (int k = 0; k < 4; ++k) {
            rr[k] = mish_fast(a3[k] + bb1a) * ssa + bb2a
                  + mish_fast(a5[k] + bb1b) * ssb + bb2b
                  + mish_fast(a7[k] + bb1c) * ssc + bb2c;
        }
        float* op = out + ((size_t)b * DIM + 64 + c) * HW;
        *(float4*)(op + (oy + y) * 64 + ox + x0) = res;
    } else {
        // ---------------- role G: k_final ----------------
        int id2 = bid / 9;                 // 0..511
        int h0 = (id2 & 31) * 2;
        int b  = id2 >> 5;
        float* yv = smem;                  // 32*128 = 4096
        float* wt = smem + 4096;           // 32*64 = 2048, o-index swizzled

        float acc[8][4];
#pragma unroll
        for (int i = 0; i < 8; ++i)
#pragma unroll
            for (int j = 0; j < 4; ++j) acc[i][j] = 0.f;

        int o0 = (tid >> 5) * 8;
        int p0 = (tid & 31) * 4;

        for (int ko = 0; ko < 64; ko += 32) {
            if (ko) __syncthreads();
            {
                int s = tid;
#pragma unroll
                for (int it = 0; it < 4; ++it, s += 256) {
                    int c = s >> 5, p4 = (s & 31) * 4;
                    size_t idx = ((size_t)b * 64 + ko + c) * HW + h0 * 64 + p4;
                    *(float4*)(yv + c * 128 + p4) = *(const float4*)(yz + idx);
                }
            }
            {
                int s = tid;
#pragma unroll
                for (int it = 0; it < 2; ++it, s += 256) {
                    int o = s >> 3, c0 = (s & 7) * 4;
#pragma unroll
                    for (int i = 0; i < 4; ++i) {
                        int cc = c0 + i;
                        int osw = o ^ (((cc >> 2) & 3) << 3);   // bank spread, b128-safe
                        wt[cc * 64 + osw] = ((const float*)(ow + o * 64 + ko + c0))[i];
                    }
                }
            }
            __syncthreads();
#pragma unroll 4
            for (int c = 0; c < 32; ++c) {
                int osw = o0 ^ (((c >> 2) & 3) << 3);
                float wv[8], xv[4];
                *(float4*)(wv)     = *(const float4*)(wt + c * 64 + osw);
                *(float4*)(wv + 4) = *(const float4*)(wt + c * 64 + osw + 4);
                *(float4*)(xv)     = *(const float4*)(yv + c * 128 + p0);
#pragma unroll
                for (int i = 0; i < 8; ++i)
#pragma unroll
                    for (int j = 0; j < 4; ++j)
                        acc[i][j] = fmaf(wv[i], xv[j], acc[i][j]);
            }
        }

#pragma unroll
        for (int i = 0; i < 8; ++i) {
            int o = o0 + i;
            float bs = base_scale[o];
            float4 u = *(const float4*)(up + ((size_t)b * 64 + o) * HW + h0 * 64 + p0);
            float4 r = make_float4(fmaf(bs, acc[i][0], u.x),
                                   fmaf(bs, acc[i][1], u.y),
                                   fmaf(bs, acc[i][2], u.z),
                                   fmaf(bs, acc[i][3], u.w));
            *(float4*)(out + ((size_t)b * DIM + o) * HW + h0 * 64 + p0) = r;
        }
    }
}

// ---------------------------------------------------------------------------
extern "C" void kernel_launch(void* const* d_in, const int* in_sizes, int n_in,
                              void* d_out, int out_size, void* d_ws, size_t ws_size,
                              hipStream_t stream) {
    (void)in_sizes; (void)n_in; (void)out_size; (void)ws_size;
    const float* x = (const float*)d_in[0];
    float* out = (float*)d_out;
    float* ws = (float*)d_ws;

    const size_t IMG = (size_t)NB * 64 * HW;   // 4,194,304 floats
    float* buf_xi   = ws;                      // xi, later reused as yz
    float* buf_z    = ws + IMG;
    float* buf_xc   = ws + 2 * IMG;
    float* buf_up   = ws + 3 * IMG;
    float* buf_p4   = ws + 4 * IMG;            // float4[2*16*4096]
    float* buf_pBC  = buf_p4 + (size_t)4 * 2 * NB * HW;
    float* buf_mean = buf_pBC + (size_t)2 * 2 * NB * HW;
    float* buf_w3   = buf_mean + 1024;
    float* buf_w5   = buf_w3 + 16 * 64 * 9;
    float* buf_w7   = buf_w5 + 16 * 64 * 25;

    // stage1: wavelet-up + mean (A) || input projection (D), interleaved
    k_stage1<<<1536, 256, 0, stream>>>(x,
        (const float*)d_in[22], (const float*)d_in[23], (const float*)d_in[24],
        buf_up, buf_mean,
        (const float*)d_in[26], buf_xi, buf_z);

    // stage2: dwconv+proj (E) || expert-mix weights (B)
    k_stage2<<<528, 256, 0, stream>>>(buf_xi,
        (const float*)d_in[27], (const float*)d_in[28], (const float*)d_in[29],
        buf_xc, (float4*)buf_p4, (float2*)buf_pBC,
        buf_mean,
        (const float*)d_in[1],  (const float*)d_in[2],  (const float*)d_in[3],
        (const float*)d_in[8],  (const float*)d_in[9],  (const float*)d_in[10],
        (const float*)d_in[15], (const float*)d_in[16], (const float*)d_in[17],
        buf_w3, buf_w5, buf_w7);

    // stage3: dual-direction selective scan -> yz (xi is dead, reuse)
    k_scan2<<<1024, 256, 0, stream>>>(buf_xc, (const float4*)buf_p4, (const float2*)buf_pBC,
        (const float*)d_in[30], (const float*)d_in[31],
        (const float*)d_in[32], (const float*)d_in[33],
        buf_z, buf_xi);

    // stage4: local conv + passthrough (C) || final GEMM (G), interleaved
    k_stage4<<<4608, 256, 0, stream>>>(x, buf_w3, buf_w5, buf_w7,
        (const float*)d_in[4],  (const float*)d_in[5],  (const float*)d_in[6],  (const float*)d_in[7],
        (const float*)d_in[11], (const float*)d_in[12], (const float*)d_in[13], (const float*)d_in[14],
        (const float*)d_in[18], (const float*)d_in[19], (const float*)d_in[20], (const float*)d_in[21],
        buf_xi, (const float*)d_in[34], (const float*)d_in[25], buf_up, out);
}

// Round 17
// 114.286 us; speedup vs baseline: 1.0517x; 1.0330x over previous
//
#include <hip/hip_runtime.h>
#include <math.h>

// Problem constants
static constexpr int NB   = 16;    // batch
static constexpr int DIM  = 256;   // total channels
static constexpr int CG   = 64;    // global-branch channels
static constexpr int HH   = 64;
static constexpr int WW   = 64;
static constexpr int HW   = HH * WW;   // 4096

// mish(x) = x*tanh(softplus(x)) = x*(t^2+2t)/(t^2+2t+2), t=e^x.
__device__ __forceinline__ float mish_fast(float x) {
    float t = __expf(fminf(x, 20.f));
    float p = __builtin_fmaf(t, t, t + t);         // t^2 + 2t
    return x * p * __builtin_amdgcn_rcpf(p + 2.f);
}
__device__ __forceinline__ float silu_f(float x) {
    return x * __builtin_amdgcn_rcpf(1.f + __expf(-x));
}
__device__ __forceinline__ float softplus_fast(float x) {
    return fmaxf(x, 0.f) + __logf(1.f + __expf(-fabsf(x)));
}

// ===========================================================================
// STAGE 1 (roles interleaved: bid%3==2 -> D, else A)
//   role A = wavelet up (register-direct Haar dec) + channel mean (wave-reduce)
//   role D = ss2d input projection GEMM (wt o-index XOR-swizzled, b128-safe)
// ===========================================================================
__global__ __launch_bounds__(256) void k_stage1(
    const float* __restrict__ x,
    const float* __restrict__ wav_w, const float* __restrict__ wav_b,
    const float* __restrict__ wav_scale,
    float* __restrict__ up, float* __restrict__ mean,
    const float* __restrict__ in_w,
    float* __restrict__ xi, float* __restrict__ z) {
    __shared__ float smem[8192];
    int bid = blockIdx.x;
    int tid = threadIdx.x;

    if (bid % 3 != 2) {
        // ---------------- role A: wavelet + mean ----------------
        int aid = (bid / 3) * 2 + (bid % 3);   // 0..1023
        int c = aid & 63, b = aid >> 6;
        float* wtb = smem;                 // 4 planes * (32*34) = 4352
        float* red = smem + 4352;          // 4
        const float* xp = x + ((size_t)b * DIM + c) * HW;

        // mean of plane (b, 64+c): float4 loads + wave shuffle reduce
        {
            const float4* lp4 = (const float4*)(x + ((size_t)b * DIM + 64 + c) * HW);
            float s = 0.f;
            for (int i = tid; i < 1024; i += 256) {
                float4 v = lp4[i];
                s += (v.x + v.y) + (v.z + v.w);
            }
#pragma unroll
            for (int off = 32; off > 0; off >>= 1) s += __shfl_xor(s, off, 64);
            if ((tid & 63) == 0) red[tid >> 6] = s;
            __syncthreads();
            if (tid == 0)
                mean[b * 64 + c] = ((red[0] + red[1]) + (red[2] + red[3])) * (1.f / HW);
        }

        // register-direct Haar dec
#pragma unroll
        for (int it = 0; it < 2; ++it) {
            int p = tid + it * 256;        // 0..511
            int h = p >> 4, w2 = p & 15;
            float4 top = *(const float4*)(xp + (2 * h) * 64 + 4 * w2);
            float4 bot = *(const float4*)(xp + (2 * h + 1) * 64 + 4 * w2);
            float a0 = top.x, b0 = top.y, c0q = bot.x, d0 = bot.y;
            float a1 = top.z, b1 = top.w, c1q = bot.z, d1 = bot.w;
            int base0 = h * 34 + 2 * w2;
            *(float2*)(wtb + 0 * 1088 + base0) =
                make_float2(0.5f * (a0 + b0 + c0q + d0), 0.5f * (a1 + b1 + c1q + d1));
            *(float2*)(wtb + 1 * 1088 + base0) =
                make_float2(0.5f * (a0 + b0 - c0q - d0), 0.5f * (a1 + b1 - c1q - d1));
            *(float2*)(wtb + 2 * 1088 + base0) =
                make_float2(0.5f * (a0 - b0 + c0q - d0), 0.5f * (a1 - b1 + c1q - d1));
            *(float2*)(wtb + 3 * 1088 + base0) =
                make_float2(0.5f * (a0 - b0 - c0q + d0), 0.5f * (a1 - b1 - c1q + d1));
        }
        __syncthreads();

        float wk[4][9], tb[4];
#pragma unroll
        for (int k = 0; k < 4; ++k) {
            int ch = c * 4 + k;
            float sc = wav_scale[ch];
#pragma unroll
            for (int j = 0; j < 9; ++j) wk[k][j] = wav_w[ch * 9 + j] * sc;
            tb[k] = wav_b[ch] * sc;
        }
        float* upp = up + ((size_t)b * CG + c) * HW;
        for (int i = tid; i < 1024; i += 256) {
            int h = i >> 5, w = i & 31;
            float tg[4];
#pragma unroll
            for (int k = 0; k < 4; ++k) {
                float s = tb[k];
#pragma unroll
                for (int dy = -1; dy <= 1; ++dy) {
                    int hh = h + dy;
                    if (hh < 0 || hh >= 32) continue;
#pragma unroll
                    for (int dx = -1; dx <= 1; ++dx) {
                        int wx = w + dx;
                        if (wx < 0 || wx >= 32) continue;
                        s = fmaf(wtb[k * 1088 + hh * 34 + wx], wk[k][(dy + 1) * 3 + (dx + 1)], s);
                    }
                }
                tg[k] = s;
            }
            float u00 = 0.5f * (tg[0] - tg[1] - tg[2] + tg[3]);
            float u01 = 0.5f * (tg[0] - tg[1] + tg[2] - tg[3]);
            float u10 = 0.5f * (tg[0] + tg[1] - tg[2] - tg[3]);
            float u11 = 0.5f * (tg[0] + tg[1] + tg[2] + tg[3]);
            *(float2*)(upp + (2 * h) * 64 + 2 * w)     = make_float2(u00, u01);
            *(float2*)(upp + (2 * h + 1) * 64 + 2 * w) = make_float2(u10, u11);
        }
    } else {
        // ---------------- role D: k_inproj ----------------
        int id2 = bid / 3;                 // 0..511
        int h0 = (id2 & 31) * 2;
        int b  = id2 >> 5;
        float* xs = smem;                  // 32*128
        float* wt = smem + 4096;           // 32*128, o-index swizzled

        float acc[8][8];
#pragma unroll
        for (int i = 0; i < 8; ++i)
#pragma unroll
            for (int j = 0; j < 8; ++j) acc[i][j] = 0.f;

        int o0 = (tid >> 4) * 8;
        int p0 = (tid & 15) * 8;

        for (int ko = 0; ko < 64; ko += 32) {
            if (ko) __syncthreads();
            {
                int s = tid;
#pragma unroll
                for (int it = 0; it < 4; ++it, s += 256) {
                    int c = s >> 5, p4 = (s & 31) * 4;
                    float4 v = *(const float4*)(x + ((size_t)b * DIM + ko + c) * HW + h0 * 64 + p4);
                    *(float4*)(xs + c * 128 + p4) = v;
                }
            }
            {
                int s = tid;
#pragma unroll
                for (int it = 0; it < 4; ++it, s += 256) {
                    int o = s >> 3, c0 = (s & 7) * 4;
#pragma unroll
                    for (int i = 0; i < 4; ++i) {
                        int cc = c0 + i;
                        int osw = o ^ (((cc >> 2) & 3) << 3);   // bank spread, b128-safe
                        wt[cc * 128 + osw] = ((const float*)(in_w + o * 64 + ko + c0))[i];
                    }
                }
            }
            __syncthreads();
#pragma unroll 4
            for (int c = 0; c < 32; ++c) {
                int osw = o0 ^ (((c >> 2) & 3) << 3);
                float xv[8], wv[8];
                *(float4*)(xv)     = *(const float4*)(xs + c * 128 + p0);
                *(float4*)(xv + 4) = *(const float4*)(xs + c * 128 + p0 + 4);
                *(float4*)(wv)     = *(const float4*)(wt + c * 128 + osw);
                *(float4*)(wv + 4) = *(const float4*)(wt + c * 128 + osw + 4);
#pragma unroll
                for (int i = 0; i < 8; ++i)
#pragma unroll
                    for (int j = 0; j < 8; ++j)
                        acc[i][j] = fmaf(wv[i], xv[j], acc[i][j]);
            }
        }

#pragma unroll
        for (int i = 0; i < 8; ++i) {
            int o = o0 + i;
            float* dst = (o < 64) ? (xi + ((size_t)b * 64 + o) * HW + h0 * 64)
                                  : (z + ((size_t)b * 64 + (o - 64)) * HW + h0 * 64);
            *(float4*)(dst + p0)     = make_float4(acc[i][0], acc[i][1], acc[i][2], acc[i][3]);
            *(float4*)(dst + p0 + 4) = make_float4(acc[i][4], acc[i][5], acc[i][6], acc[i][7]);
        }
    }
}

// ===========================================================================
// STAGE 2: role E (blocks 0..511) = fused dwconv+silu -> xc, projections
//          role B (blocks 512..527) = all three expert-mixes
// ===========================================================================
__global__ __launch_bounds__(256) void k_stage2(
    const float* __restrict__ xi,
    const float* __restrict__ cw, const float* __restrict__ cb,
    const float* __restrict__ xpw,
    float* __restrict__ xc, float4* __restrict__ proj4, float2* __restrict__ projBC,
    const float* __restrict__ mean,
    const float* __restrict__ ew3, const float* __restrict__ gw3, const float* __restrict__ g13,
    const float* __restrict__ ew5, const float* __restrict__ gw5, const float* __restrict__ g15,
    const float* __restrict__ ew7, const float* __restrict__ gw7, const float* __restrict__ g17,
    float* __restrict__ w3o, float* __restrict__ w5o, float* __restrict__ w7o) {
    __shared__ float smem[12608];
    int bid = blockIdx.x;
    int tid = threadIdx.x;

    if (bid < 512) {
        // ---------------- role E: k_convproj ----------------
        int h0 = (bid & 31) * 2;
        int b  = bid >> 5;
        float* xs  = smem;                 // 32*264 = 8448
        float* xcs = smem + 8448;          // 32*130 = 4160

        int dir = tid >> 7;
        int px  = tid & 127;
        float acc0 = 0.f, acc1 = 0.f, acc2 = 0.f, acc3 = 0.f, acc4 = 0.f, acc5 = 0.f;

        int cl_c = tid >> 3;
        int p0_c = (tid & 7) * 16;
        int row_c = p0_c >> 6;
        int wb_c  = p0_c & 63;

        for (int ch0 = 0; ch0 < 64; ch0 += 32) {
            if (ch0) __syncthreads();
            {
                int s = tid;
#pragma unroll
                for (int it = 0; it < 8; ++it, s += 256) {
                    int c = s >> 6;
                    int rem = s & 63;
                    int r = rem >> 4, w4 = (rem & 15) * 4;
                    int gh = h0 - 1 + r;
                    float4 v = make_float4(0.f, 0.f, 0.f, 0.f);
                    if (gh >= 0 && gh < 64)
                        v = *(const float4*)(xi + ((size_t)b * 64 + ch0 + c) * HW + gh * 64 + w4);
                    float* dp = xs + c * 264 + r * 66 + 1 + w4;
                    dp[0] = v.x; dp[1] = v.y; dp[2] = v.z; dp[3] = v.w;
                }
                if (tid < 128) {
                    int cl = tid >> 2, r = tid & 3;
                    xs[cl * 264 + r * 66 + 0]  = 0.f;
                    xs[cl * 264 + r * 66 + 65] = 0.f;
                }
            }
            __syncthreads();

            {
                float wk[9];
#pragma unroll
                for (int j = 0; j < 9; ++j) wk[j] = cw[(ch0 + cl_c) * 9 + j];
                float bias = cb[ch0 + cl_c];
                float accr[16];
#pragma unroll
                for (int k = 0; k < 16; ++k) accr[k] = bias;
#pragma unroll
                for (int dy = 0; dy < 3; ++dy) {
                    const float* rp = xs + cl_c * 264 + (row_c + dy) * 66 + wb_c;
                    float r[18];
#pragma unroll
                    for (int q = 0; q < 18; ++q) r[q] = rp[q];
#pragma unroll
                    for (int k = 0; k < 16; ++k)
#pragma unroll
                        for (int dx = 0; dx < 3; ++dx)
                            accr[k] = fmaf(r[k + dx], wk[dy * 3 + dx], accr[k]);
                }
#pragma unroll
                for (int k = 0; k < 16; ++k)
                    xcs[cl_c * 130 + p0_c + k] = silu_f(accr[k]);
            }
            __syncthreads();

            {
                int s = tid;
#pragma unroll
                for (int it = 0; it < 4; ++it, s += 256) {
                    int c = s >> 5, pq = (s & 31) * 4;
                    const float* sp = xcs + c * 130 + pq;
                    *(float4*)(xc + ((size_t)b * 64 + ch0 + c) * HW + h0 * 64 + pq) =
                        make_float4(sp[0], sp[1], sp[2], sp[3]);
                }
            }
            {
                const float* wp = xpw + dir * 6 * 64 + ch0;
#pragma unroll 8
                for (int c = 0; c < 32; ++c) {
                    float xv = xcs[c * 130 + px];
                    acc0 = fmaf(xv, wp[0 * 64 + c], acc0);
                    acc1 = fmaf(xv, wp[1 * 64 + c], acc1);
                    acc2 = fmaf(xv, wp[2 * 64 + c], acc2);
                    acc3 = fmaf(xv, wp[3 * 64 + c], acc3);
                    acc4 = fmaf(xv, wp[4 * 64 + c], acc4);
                    acc5 = fmaf(xv, wp[5 * 64 + c], acc5);
                }
            }
        }

        int h = h0 + (px >> 6), w = px & 63;
        int l = (dir == 0) ? (h * 64 + w) : (w * 64 + h);
        size_t base = ((size_t)dir * NB + b) * HW + l;
        proj4[base]  = make_float4(acc0, acc1, acc2, acc3);
        projBC[base] = make_float2(acc4, acc5);
    } else {
        // ---------------- role B: k_weff_all ----------------
        int b = bid - 512;
        int c = tid;
        float* m = smem;
        float* g = smem + 64;
        if (c < 64) m[c] = mean[b * 64 + c];
        __syncthreads();
        const float rs = rsqrtf(1.f + 1e-5f);

#define WEFF_SECT(GW, EW, G1, OUT, K2)                                        \
        {                                                                     \
            if (c < 4) {                                                      \
                float l = 0.f;                                                \
                for (int cc = 0; cc < 64; ++cc) l += m[cc] * GW[c * 64 + cc]; \
                g[c] = l;                                                     \
            }                                                                 \
            __syncthreads();                                                  \
            if (c == 0) {                                                     \
                float mx = fmaxf(fmaxf(g[0], g[1]), fmaxf(g[2], g[3]));       \
                float e0 = expf(g[0] - mx), e1 = expf(g[1] - mx);             \
                float e2 = expf(g[2] - mx), e3 = expf(g[3] - mx);             \
                float inv = 1.f / (e0 + e1 + e2 + e3);                        \
                g[0] = e0 * inv; g[1] = e1 * inv; g[2] = e2 * inv; g[3] = e3 * inv; \
            }                                                                 \
            __syncthreads();                                                  \
            if (c < 64) {                                                     \
                float g1s = G1[c] * rs;                                       \
                for (int kk = 0; kk < K2; ++kk) {                             \
                    float w = 0.f;                                            \
                    for (int e = 0; e < 4; ++e) w += g[e] * EW[(e * 64 + c) * K2 + kk]; \
                    OUT[(b * 64 + c) * K2 + kk] = w * g1s;                    \
                }                                                             \
            }                                                                 \
            __syncthreads();                                                  \
        }

        WEFF_SECT(gw3, ew3, g13, w3o, 9)
        WEFF_SECT(gw5, ew5, g15, w5o, 25)
        WEFF_SECT(gw7, ew7, g17, w7o, 49)
#undef WEFF_SECT
    }
}

// ===========================================================================
// STAGE 3: selective scan, both directions per block (unchanged).
// ===========================================================================
__global__ __launch_bounds__(256) void k_scan2(const float* __restrict__ xc,
                                               const float4* __restrict__ proj4,
                                               const float2* __restrict__ projBC,
                                               const float* __restrict__ dt_w,
                                               const float* __restrict__ dt_b,
                                               const float* __restrict__ A_log,
                                               const float* __restrict__ Dp,
                                               const float* __restrict__ z,
                                               float* __restrict__ yz) {
    int wave = threadIdx.x >> 6;
    int lane = threadIdx.x & 63;
    int wid = blockIdx.x;                // b*64 + d
    int b = wid >> 6;
    int d = wid & 63;

    __shared__ float ut[64 * 65];
    __shared__ float al[4][1088];
    __shared__ float bl[4][1088];
    __shared__ float aggA[4], aggB[4];

    const float* uplane = xc + ((size_t)b * 64 + d) * HW;
    const float4* up4 = (const float4*)uplane;
#pragma unroll
    for (int q = 0; q < 4; ++q) {
        int s = q * 256 + threadIdx.x;
        float4 v = up4[s];
        int r = s >> 4, c0 = (s & 15) * 4;
        float* p = ut + r * 65 + c0;
        p[0] = v.x; p[1] = v.y; p[2] = v.z; p[3] = v.w;
    }
    __syncthreads();

    int ch = wave;
    float* a_my = al[wave];
    float* b_my = bl[wave];
    float y0r[16];

    // ================= DIR 0 =================
    {
        float4 wv = *(const float4*)(dt_w + d * 4);
        float db = dt_b[d];
        float A = -__expf(A_log[d]);
        float Dv = Dp[d];
        const float4* p4 = proj4 + (size_t)b * HW;
        const float2* pBC = projBC + (size_t)b * HW;

        float uv[16], cm[16];
#pragma unroll
        for (int j = 0; j < 16; ++j) {
            int el = j * 64 + lane;
            int e  = ch * 1024 + el;
            float4 t4 = p4[e];
            float2 t2 = pBC[e];
            float u = ut[(ch * 16 + j) * 65 + lane];
            uv[j] = u; cm[j] = t2.y;
            float pre = fmaf(t4.x, wv.x, fmaf(t4.y, wv.y,
                        fmaf(t4.z, wv.z, fmaf(t4.w, wv.w, db))));
            float delta = softplus_fast(pre);
            float aj = __expf(delta * A);
            float bj = delta * t2.x * u;
            int idx = (el >> 4) * 17 + (el & 15);
            a_my[idx] = aj;
            b_my[idx] = bj;
        }
        __builtin_amdgcn_wave_barrier();

        float a[16], bb[16];
#pragma unroll
        for (int j = 0; j < 16; ++j) {
            a[j]  = a_my[lane * 17 + j];
            bb[j] = b_my[lane * 17 + j];
        }
        float As = 1.f, Bs = 0.f;
#pragma unroll
        for (int j = 0; j < 16; ++j) { Bs = fmaf(a[j], Bs, bb[j]); As *= a[j]; }
        float Ai = As, Bi = Bs;
#pragma unroll
        for (int off = 1; off < 64; off <<= 1) {
            float ap = __shfl_up(Ai, (unsigned)off, 64);
            float bp = __shfl_up(Bi, (unsigned)off, 64);
            if (lane >= off) { Bi = fmaf(Ai, bp, Bi); Ai *= ap; }
        }
        if (lane == 63) { aggA[wave] = Ai; aggB[wave] = Bi; }
        __syncthreads();
        float carry = 0.f;
        for (int k = 0; k < wave; ++k) carry = fmaf(aggA[k], carry, aggB[k]);
        float ap1 = __shfl_up(Ai, 1, 64);
        float bp1 = __shfl_up(Bi, 1, 64);
        float h = (lane == 0) ? carry : fmaf(ap1, carry, bp1);
#pragma unroll
        for (int j = 0; j < 16; ++j) {
            h = fmaf(a[j], h, bb[j]);
            a_my[lane * 17 + j] = h;
        }
        __builtin_amdgcn_wave_barrier();
#pragma unroll
        for (int j = 0; j < 16; ++j) {
            int el = j * 64 + lane;
            float hv = a_my[(el >> 4) * 17 + (el & 15)];
            y0r[j] = fmaf(hv, cm[j], Dv * uv[j]);
        }
    }
    __syncthreads();

    // ================= DIR 1 =================
    {
        int pd = 64 + d;
        float4 wv = *(const float4*)(dt_w + pd * 4);
        float db = dt_b[pd];
        float A = -__expf(A_log[pd]);
        float Dv = Dp[pd];
        const float4* p4 = proj4 + ((size_t)NB + b) * HW;
        const float2* pBC = projBC + ((size_t)NB + b) * HW;

        float uv[16], cm[16];
#pragma unroll
        for (int j = 0; j < 16; ++j) {
            int el = j * 64 + lane;
            int e  = ch * 1024 + el;
            float4 t4 = p4[e];
            float2 t2 = pBC[e];
            float u = ut[lane * 65 + (ch * 16 + j)];
            uv[j] = u; cm[j] = t2.y;
            float pre = fmaf(t4.x, wv.x, fmaf(t4.y, wv.y,
                        fmaf(t4.z, wv.z, fmaf(t4.w, wv.w, db))));
            float delta = softplus_fast(pre);
            float aj = __expf(delta * A);
            float bj = delta * t2.x * u;
            int idx = (el >> 4) * 17 + (el & 15);
            a_my[idx] = aj;
            b_my[idx] = bj;
        }
        __builtin_amdgcn_wave_barrier();

        float a[16], bb[16];
#pragma unroll
        for (int j = 0; j < 16; ++j) {
            a[j]  = a_my[lane * 17 + j];
            bb[j] = b_my[lane * 17 + j];
        }
        float As = 1.f, Bs = 0.f;
#pragma unroll
        for (int j = 0; j < 16; ++j) { Bs = fmaf(a[j], Bs, bb[j]); As *= a[j]; }
        float Ai = As, Bi = Bs;
#pragma unroll
        for (int off = 1; off < 64; off <<= 1) {
            float ap = __shfl_up(Ai, (unsigned)off, 64);
            float bp = __shfl_up(Bi, (unsigned)off, 64);
            if (lane >= off) { Bi = fmaf(Ai, bp, Bi); Ai *= ap; }
        }
        if (lane == 63) { aggA[wave] = Ai; aggB[wave] = Bi; }
        __syncthreads();
        float carry = 0.f;
        for (int k = 0; k < wave; ++k) carry = fmaf(aggA[k], carry, aggB[k]);
        float ap1 = __shfl_up(Ai, 1, 64);
        float bp1 = __shfl_up(Bi, 1, 64);
        float h = (lane == 0) ? carry : fmaf(ap1, carry, bp1);
#pragma unroll
        for (int j = 0; j < 16; ++j) {
            h = fmaf(a[j], h, bb[j]);
            a_my[lane * 17 + j] = h;
        }
        __builtin_amdgcn_wave_barrier();
#pragma unroll
        for (int j = 0; j < 16; ++j) {
            int el = j * 64 + lane;
            float hv = a_my[(el >> 4) * 17 + (el & 15)];
            ut[lane * 65 + (ch * 16 + j)] = fmaf(hv, cm[j], Dv * uv[j]);
        }
    }
    __syncthreads();

    const float* zp = z + ((size_t)b * 64 + d) * HW;
    float* yp = yz + ((size_t)b * 64 + d) * HW;
#pragma unroll
    for (int j = 0; j < 16; ++j) {
        int e = ch * 1024 + j * 64 + lane;
        float y1v = ut[(ch * 16 + j) * 65 + lane];
        float zz = zp[e];
        yp[e] = (y0r[j] + y1v) * silu_f(zz);
    }
}

// ===========================================================================
// STAGE 4 (roles interleaved: bid%5==4 -> G, else C)
//   role C = local conv, 2-output-row groups w/ shared window rows
//            + passthrough copy (out channels [64:256]). 2048 blocks.
//   role G = final GEMM (wt o-index XOR-swizzled) + up add (out [0:64]).
// ===========================================================================
__global__ __launch_bounds__(256) void k_stage4(
    const float* __restrict__ x,
    const float* __restrict__ w3, const float* __restrict__ w5, const float* __restrict__ w7,
    const float* __restrict__ b1_0, const float* __restrict__ pw0,
    const float* __restrict__ g2_0, const float* __restrict__ b2_0,
    const float* __restrict__ b1_1, const float* __restrict__ pw1,
    const float* __restrict__ g2_1, const float* __restrict__ b2_1,
    const float* __restrict__ b1_2, const float* __restrict__ pw2,
    const float* __restrict__ g2_2, const float* __restrict__ b2_2,
    const float* __restrict__ yz, const float* __restrict__ ow,
    const float* __restrict__ base_scale, const float* __restrict__ up,
    float* __restrict__ out) {
    __shared__ float smem[6144];
    int bid = blockIdx.x;
    int tid = threadIdx.x;

    if (bid % 5 != 4) {
        // ---------------- role C: 32-row half-plane conv ----------------
        int cidx = (bid / 5) * 4 + (bid % 5);   // 0..2047
        int half = cidx & 1;
        int c = (cidx >> 1) & 63;
        int b = cidx >> 7;
        int oy = half * 32;
        float* t = smem;                   // 38 rows x 72 stride = 2736 floats
        const float* xp = x + ((size_t)b * DIM + 64 + c) * HW;

        // zero pass (684 float4 covers whole tile incl. halo cols)
        {
            float4 z4 = make_float4(0.f, 0.f, 0.f, 0.f);
            for (int i = tid; i < 684; i += 256) ((float4*)t)[i] = z4;
        }
        // fused passthrough copy (independent of LDS)
        {
            const float4* x4 = (const float4*)x;
            float4* o4 = (float4*)out;
            int base = cidx * 1024;
#pragma unroll
            for (int it = 0; it < 4; ++it) {
                int idx = base + it * 256 + tid;
                int bb = idx >> 17;
                int r  = idx & 131071;
                int gi = bb * 262144 + 131072 + r;
                o4[gi] = x4[gi];
            }
        }
        __syncthreads();
        // data pass: rows -3..34 (tile rows 0..37), data at cols 4..67
        {
            for (int i = tid; i < 608; i += 256) {
                int tr = i >> 4, q = (i & 15) * 4;
                int gy = oy + tr - 3;
                if (gy >= 0 && gy < 64)
                    *(float4*)(t + tr * 72 + 4 + q) = *(const float4*)(xp + gy * 64 + q);
            }
        }
        // block-uniform weights -> SGPRs
        const float* w3p = w3 + (b * 64 + c) * 9;
        const float* w5p = w5 + (b * 64 + c) * 25;
        const float* w7p = w7 + (b * 64 + c) * 49;
        float W3r[9], W5r[25], W7r[49];
#pragma unroll
        for (int j = 0; j < 9; ++j)  W3r[j] = w3p[j];
#pragma unroll
        for (int j = 0; j < 25; ++j) W5r[j] = w5p[j];
#pragma unroll
        for (int j = 0; j < 49; ++j) W7r[j] = w7p[j];
        __syncthreads();

        const float rs = rsqrtf(1.f + 1e-5f);
        float bb1a = b1_0[c], bb1b = b1_1[c], bb1c = b1_2[c];
        float ssa = pw0[c] * g2_0[c] * rs, ssb = pw1[c] * g2_1[c] * rs, ssc = pw2[c] * g2_2[c] * rs;
        float bb2a = b2_0[c], bb2b = b2_1[c], bb2c = b2_2[c];

        int r  = tid >> 4;                 // 0..15 -> rows 2r, 2r+1
        int x0 = (tid & 15) * 4;           // 0..60

        float a3[2][4] = {{0.f,0.f,0.f,0.f},{0.f,0.f,0.f,0.f}};
        float a5[2][4] = {{0.f,0.f,0.f,0.f},{0.f,0.f,0.f,0.f}};
        float a7[2][4] = {{0.f,0.f,0.f,0.f},{0.f,0.f,0.f,0.f}};

        // window rows j=0..7: tile row 2r+j (covers input rows 2r-3..2r+4).
        // out-row 0 uses dy=j (j<=6); out-row 1 uses dy=j-1 (j>=1).
        // r12[m] = col x0-4+m; a7 uses r[k+dx+1], a5 r[k+dx+2], a3 r[k+dx+3].
#pragma unroll
        for (int j = 0; j < 8; ++j) {
            const float4* rp = (const float4*)(t + (2 * r + j) * 72 + x0);
            float4 q0 = rp[0], q1 = rp[1], q2 = rp[2];
            float rr[12] = {q0.x, q0.y, q0.z, q0.w, q1.x, q1.y, q1.z, q1.w,
                            q2.x, q2.y, q2.z, q2.w};
            if (j <= 6) {
#pragma unroll
                for (int k = 0; k < 4; ++k)
#pragma unroll
                    for (int dx = 0; dx < 7; ++dx)
                        a7[0][k] = fmaf(rr[k + dx + 1], W7r[j * 7 + dx], a7[0][k]);
                if (j >= 1 && j <= 5) {
#pragma unroll
                    for (int k = 0; k < 4; ++k)
#pragma unroll
                        for (int dx = 0; dx < 5; ++dx)
                            a5[0][k] = fmaf(rr[k + dx + 2], W5r[(j - 1) * 5 + dx], a5[0][k]);
                }
                if (j >= 2 && j <= 4) {
#pragma unroll
                    for (int k = 0; k < 4; ++k)
#pragma unroll
                        for (int dx = 0; dx < 3; ++dx)
                            a3[0][k] = fmaf(rr[k + dx + 3], W3r[(j - 2) * 3 + dx], a3[0][k]);
                }
            }
            if (j >= 1) {
#pragma unroll
                for (int k = 0; k < 4; ++k)
#pragma unroll
                    for (int dx = 0; dx < 7; ++dx)
                        a7[1][k] = fmaf(rr[k + dx + 1], W7r[(j - 1) * 7 + dx], a7[1][k]);
                if (j >= 2 && j <= 6) {
#pragma unroll
                    for (int k = 0; k < 4; ++k)
#pragma unroll
                        for (int dx = 0; dx < 5; ++dx)
                            a5[1][k] = fmaf(rr[k + dx + 2], W5r[(j - 2) * 5 + dx], a5[1][k]);
                }
                if (j >= 3 && j <= 5) {
#pragma unroll
                    for (int k = 0; k < 4; ++k)
#pragma unroll
                        for (int dx = 0; dx < 3; ++dx)
                            a3[1][k] = fmaf(rr[k + dx + 3], W3r[(j - 3) * 3 + dx], a3[1][k]);
                }
            }
        }

        float* op = out + ((size_t)b * DIM + 64 + c) * HW;
#pragma unroll
        for (int rr2 = 0; rr2 < 2; ++rr2) {
            float4 res;
            float* rv = (float*)&res;
#pragma unroll
            for (int k = 0; k < 4; ++k) {
                rv[k] = mish_fast(a3[rr2][k] + bb1a) * ssa + bb2a
                      + mish_fast(a5[rr2][k] + bb1b) * ssb + bb2b
                      + mish_fast(a7[rr2][k] + bb1c) * ssc + bb2c;
            }
            *(float4*)(op + (oy + 2 * r + rr2) * 64 + x0) = res;
        }
    } else {
        // ---------------- role G: k_final ----------------
        int id2 = bid / 5;                 // 0..511
        int h0 = (id2 & 31) * 2;
        int b  = id2 >> 5;
        float* yv = smem;                  // 32*128 = 4096
        float* wt = smem + 4096;           // 32*64 = 2048, o-index swizzled

        float acc[8][4];
#pragma unroll
        for (int i = 0; i < 8; ++i)
#pragma unroll
            for (int j = 0; j < 4; ++j) acc[i][j] = 0.f;

        int o0 = (tid >> 5) * 8;
        int p0 = (tid & 31) * 4;

        for (int ko = 0; ko < 64; ko += 32) {
            if (ko) __syncthreads();
            {
                int s = tid;
#pragma unroll
                for (int it = 0; it < 4; ++it, s += 256) {
                    int c = s >> 5, p4 = (s & 31) * 4;
                    size_t idx = ((size_t)b * 64 + ko + c) * HW + h0 * 64 + p4;
                    *(float4*)(yv + c * 128 + p4) = *(const float4*)(yz + idx);
                }
            }
            {
                int s = tid;
#pragma unroll
                for (int it = 0; it < 2; ++it, s += 256) {
                    int o = s >> 3, c0 = (s & 7) * 4;
#pragma unroll
                    for (int i = 0; i < 4; ++i) {
                        int cc = c0 + i;
                        int osw = o ^ (((cc >> 2) & 3) << 3);   // bank spread, b128-safe
                        wt[cc * 64 + osw] = ((const float*)(ow + o * 64 + ko + c0))[i];
                    }
                }
            }
            __syncthreads();
#pragma unroll 4
            for (int c = 0; c < 32; ++c) {
                int osw = o0 ^ (((c >> 2) & 3) << 3);
                float wv[8], xv[4];
                *(float4*)(wv)     = *(const float4*)(wt + c * 64 + osw);
                *(float4*)(wv + 4) = *(const float4*)(wt + c * 64 + osw + 4);
                *(float4*)(xv)     = *(const float4*)(yv + c * 128 + p0);
#pragma unroll
                for (int i = 0; i < 8; ++i)
#pragma unroll
                    for (int j = 0; j < 4; ++j)
                        acc[i][j] = fmaf(wv[i], xv[j], acc[i][j]);
            }
        }

#pragma unroll
        for (int i = 0; i < 8; ++i) {
            int o = o0 + i;
            float bs = base_scale[o];
            float4 u = *(const float4*)(up + ((size_t)b * 64 + o) * HW + h0 * 64 + p0);
            float4 r = make_float4(fmaf(bs, acc[i][0], u.x),
                                   fmaf(bs, acc[i][1], u.y),
                                   fmaf(bs, acc[i][2], u.z),
                                   fmaf(bs, acc[i][3], u.w));
            *(float4*)(out + ((size_t)b * DIM + o) * HW + h0 * 64 + p0) = r;
        }
    }
}

// ---------------------------------------------------------------------------
extern "C" void kernel_launch(void* const* d_in, const int* in_sizes, int n_in,
                              void* d_out, int out_size, void* d_ws, size_t ws_size,
                              hipStream_t stream) {
    (void)in_sizes; (void)n_in; (void)out_size; (void)ws_size;
    const float* x = (const float*)d_in[0];
    float* out = (float*)d_out;
    float* ws = (float*)d_ws;

    const size_t IMG = (size_t)NB * 64 * HW;   // 4,194,304 floats
    float* buf_xi   = ws;                      // xi, later reused as yz
    float* buf_z    = ws + IMG;
    float* buf_xc   = ws + 2 * IMG;
    float* buf_up   = ws + 3 * IMG;
    float* buf_p4   = ws + 4 * IMG;            // float4[2*16*4096]
    float* buf_pBC  = buf_p4 + (size_t)4 * 2 * NB * HW;
    float* buf_mean = buf_pBC + (size_t)2 * 2 * NB * HW;
    float* buf_w3   = buf_mean + 1024;
    float* buf_w5   = buf_w3 + 16 * 64 * 9;
    float* buf_w7   = buf_w5 + 16 * 64 * 25;

    // stage1: wavelet-up + mean (A) || input projection (D), interleaved
    k_stage1<<<1536, 256, 0, stream>>>(x,
        (const float*)d_in[22], (const float*)d_in[23], (const float*)d_in[24],
        buf_up, buf_mean,
        (const float*)d_in[26], buf_xi, buf_z);

    // stage2: dwconv+proj (E) || expert-mix weights (B)
    k_stage2<<<528, 256, 0, stream>>>(buf_xi,
        (const float*)d_in[27], (const float*)d_in[28], (const float*)d_in[29],
        buf_xc, (float4*)buf_p4, (float2*)buf_pBC,
        buf_mean,
        (const float*)d_in[1],  (const float*)d_in[2],  (const float*)d_in[3],
        (const float*)d_in[8],  (const float*)d_in[9],  (const float*)d_in[10],
        (const float*)d_in[15], (const float*)d_in[16], (const float*)d_in[17],
        buf_w3, buf_w5, buf_w7);

    // stage3: dual-direction selective scan -> yz (xi is dead, reuse)
    k_scan2<<<1024, 256, 0, stream>>>(buf_xc, (const float4*)buf_p4, (const float2*)buf_pBC,
        (const float*)d_in[30], (const float*)d_in[31],
        (const float*)d_in[32], (const float*)d_in[33],
        buf_z, buf_xi);

    // stage4: local conv + passthrough (C) || final GEMM (G), interleaved
    k_stage4<<<2560, 256, 0, stream>>>(x, buf_w3, buf_w5, buf_w7,
        (const float*)d_in[4],  (const float*)d_in[5],  (const float*)d_in[6],  (const float*)d_in[7],
        (const float*)d_in[11], (const float*)d_in[12], (const float*)d_in[13], (const float*)d_in[14],
        (const float*)d_in[18], (const float*)d_in[19], (const float*)d_in[20], (const float*)d_in[21],
        buf_xi, (const float*)d_in[34], (const float*)d_in[25], buf_up, out);
}

// Round 18
// 113.713 us; speedup vs baseline: 1.0570x; 1.0050x over previous
//
#include <hip/hip_runtime.h>
#include <math.h>

// Problem constants
static constexpr int NB   = 16;    // batch
static constexpr int DIM  = 256;   // total channels
static constexpr int CG   = 64;    // global-branch channels
static constexpr int HH   = 64;
static constexpr int WW   = 64;
static constexpr int HW   = HH * WW;   // 4096

// mish(x) = x*tanh(softplus(x)) = x*(t^2+2t)/(t^2+2t+2), t=e^x.
__device__ __forceinline__ float mish_fast(float x) {
    float t = __expf(fminf(x, 20.f));
    float p = __builtin_fmaf(t, t, t + t);         // t^2 + 2t
    return x * p * __builtin_amdgcn_rcpf(p + 2.f);
}
__device__ __forceinline__ float silu_f(float x) {
    return x * __builtin_amdgcn_rcpf(1.f + __expf(-x));
}
__device__ __forceinline__ float softplus_fast(float x) {
    return fmaxf(x, 0.f) + __logf(1.f + __expf(-fabsf(x)));
}

// ===========================================================================
// STAGE 1 (bid%5==4 -> D, else A)
//   role A = wavelet up HALF-PLANE (16 wt-rows + halo) + partial channel mean
//   role D = input projection GEMM, K-16 chunks (16KB LDS union)
// ===========================================================================
__global__ __launch_bounds__(256) void k_stage1(
    const float* __restrict__ x,
    const float* __restrict__ wav_w, const float* __restrict__ wav_b,
    const float* __restrict__ wav_scale,
    float* __restrict__ up, float* __restrict__ meanp,
    const float* __restrict__ in_w,
    float* __restrict__ xi, float* __restrict__ z) {
    __shared__ float smem[4096];
    int bid = blockIdx.x;
    int tid = threadIdx.x;

    if (bid % 5 != 4) {
        // ---------------- role A: half-plane wavelet + partial mean ----------------
        int aid = (bid / 5) * 4 + (bid % 5);   // 0..2047
        int half = aid & 1;
        int c = (aid >> 1) & 63;
        int b = aid >> 7;
        int hs = half * 16;                // wt-row output range [hs, hs+16)
        float* wtb = smem;                 // 4 planes * (18*34) = 2448
        float* red = smem + 2448;          // 4
        const float* xp = x + ((size_t)b * DIM + c) * HW;

        // partial mean of plane (b, 64+c), rows half*32 .. half*32+31
        {
            const float4* lp4 = (const float4*)(x + ((size_t)b * DIM + 64 + c) * HW
                                                + half * 32 * 64);
            float s = 0.f;
#pragma unroll
            for (int it = 0; it < 2; ++it) {
                float4 v = lp4[tid + it * 256];
                s += (v.x + v.y) + (v.z + v.w);
            }
#pragma unroll
            for (int off = 32; off > 0; off >>= 1) s += __shfl_xor(s, off, 64);
            if ((tid & 63) == 0) red[tid >> 6] = s;
            __syncthreads();
            if (tid == 0)
                meanp[half * 1024 + b * 64 + c] =
                    ((red[0] + red[1]) + (red[2] + red[3])) * (1.f / HW);
        }

        // Haar dec for wt rows hs-1..hs+16 (tile rows 0..17); OOR rows skipped
#pragma unroll
        for (int it = 0; it < 2; ++it) {
            int p = tid + it * 256;        // need 288
            if (p < 288) {
                int tr = p >> 4, w2 = p & 15;
                int hr = hs - 1 + tr;
                if (hr >= 0 && hr < 32) {
                    float4 top = *(const float4*)(xp + (2 * hr) * 64 + 4 * w2);
                    float4 bot = *(const float4*)(xp + (2 * hr + 1) * 64 + 4 * w2);
                    float a0 = top.x, b0 = top.y, c0q = bot.x, d0 = bot.y;
                    float a1 = top.z, b1 = top.w, c1q = bot.z, d1 = bot.w;
                    int base0 = tr * 34 + 2 * w2;
                    *(float2*)(wtb + 0 * 612 + base0) =
                        make_float2(0.5f * (a0 + b0 + c0q + d0), 0.5f * (a1 + b1 + c1q + d1));
                    *(float2*)(wtb + 1 * 612 + base0) =
                        make_float2(0.5f * (a0 + b0 - c0q - d0), 0.5f * (a1 + b1 - c1q - d1));
                    *(float2*)(wtb + 2 * 612 + base0) =
                        make_float2(0.5f * (a0 - b0 + c0q - d0), 0.5f * (a1 - b1 + c1q - d1));
                    *(float2*)(wtb + 3 * 612 + base0) =
                        make_float2(0.5f * (a0 - b0 - c0q + d0), 0.5f * (a1 - b1 - c1q + d1));
                }
            }
        }
        __syncthreads();

        float wk[4][9], tb[4];
#pragma unroll
        for (int k = 0; k < 4; ++k) {
            int ch = c * 4 + k;
            float sc = wav_scale[ch];
#pragma unroll
            for (int j = 0; j < 9; ++j) wk[k][j] = wav_w[ch * 9 + j] * sc;
            tb[k] = wav_b[ch] * sc;
        }
        float* upp = up + ((size_t)b * CG + c) * HW;
#pragma unroll
        for (int it = 0; it < 2; ++it) {
            int i = tid + it * 256;        // 512 outputs: 16 rows x 32 cols
            int hl = i >> 5, w = i & 31;
            int h = hs + hl;
            float tg[4];
#pragma unroll
            for (int k = 0; k < 4; ++k) {
                float s = tb[k];
#pragma unroll
                for (int dy = -1; dy <= 1; ++dy) {
                    int hh = h + dy;
                    if (hh < 0 || hh >= 32) continue;
                    int trr = hh - (hs - 1);       // 0..17
#pragma unroll
                    for (int dx = -1; dx <= 1; ++dx) {
                        int wx = w + dx;
                        if (wx < 0 || wx >= 32) continue;
                        s = fmaf(wtb[k * 612 + trr * 34 + wx], wk[k][(dy + 1) * 3 + (dx + 1)], s);
                    }
                }
                tg[k] = s;
            }
            float u00 = 0.5f * (tg[0] - tg[1] - tg[2] + tg[3]);
            float u01 = 0.5f * (tg[0] - tg[1] + tg[2] - tg[3]);
            float u10 = 0.5f * (tg[0] + tg[1] - tg[2] - tg[3]);
            float u11 = 0.5f * (tg[0] + tg[1] + tg[2] + tg[3]);
            *(float2*)(upp + (2 * h) * 64 + 2 * w)     = make_float2(u00, u01);
            *(float2*)(upp + (2 * h + 1) * 64 + 2 * w) = make_float2(u10, u11);
        }
    } else {
        // ---------------- role D: k_inproj (K-16 chunks) ----------------
        int did = bid / 5;                 // 0..511
        int h0 = (did & 31) * 2;
        int b  = did >> 5;
        float* xs = smem;                  // 16*128 = 2048
        float* wt = smem + 2048;           // 16*128 = 2048, o-swizzled

        float acc[8][8];
#pragma unroll
        for (int i = 0; i < 8; ++i)
#pragma unroll
            for (int j = 0; j < 8; ++j) acc[i][j] = 0.f;

        int o0 = (tid >> 4) * 8;
        int p0 = (tid & 15) * 8;

        for (int ko = 0; ko < 64; ko += 16) {
            if (ko) __syncthreads();
            {
                int s = tid;
#pragma unroll
                for (int it = 0; it < 2; ++it, s += 256) {
                    int c = s >> 5, p4 = (s & 31) * 4;
                    float4 v = *(const float4*)(x + ((size_t)b * DIM + ko + c) * HW + h0 * 64 + p4);
                    *(float4*)(xs + c * 128 + p4) = v;
                }
            }
            {
                int s = tid;
#pragma unroll
                for (int it = 0; it < 2; ++it, s += 256) {
                    int o = s >> 2, c0 = (s & 3) * 4;
                    float4 v = *(const float4*)(in_w + o * 64 + ko + c0);
#pragma unroll
                    for (int i = 0; i < 4; ++i) {
                        int cc = c0 + i;
                        int osw = o ^ (((cc >> 2) & 3) << 3);
                        wt[cc * 128 + osw] = ((const float*)&v)[i];
                    }
                }
            }
            __syncthreads();
#pragma unroll 4
            for (int c = 0; c < 16; ++c) {
                int osw = o0 ^ (((c >> 2) & 3) << 3);
                float xv[8], wv[8];
                *(float4*)(xv)     = *(const float4*)(xs + c * 128 + p0);
                *(float4*)(xv + 4) = *(const float4*)(xs + c * 128 + p0 + 4);
                *(float4*)(wv)     = *(const float4*)(wt + c * 128 + osw);
                *(float4*)(wv + 4) = *(const float4*)(wt + c * 128 + osw + 4);
#pragma unroll
                for (int i = 0; i < 8; ++i)
#pragma unroll
                    for (int j = 0; j < 8; ++j)
                        acc[i][j] = fmaf(wv[i], xv[j], acc[i][j]);
            }
        }

#pragma unroll
        for (int i = 0; i < 8; ++i) {
            int o = o0 + i;
            float* dst = (o < 64) ? (xi + ((size_t)b * 64 + o) * HW + h0 * 64)
                                  : (z + ((size_t)b * 64 + (o - 64)) * HW + h0 * 64);
            *(float4*)(dst + p0)     = make_float4(acc[i][0], acc[i][1], acc[i][2], acc[i][3]);
            *(float4*)(dst + p0 + 4) = make_float4(acc[i][4], acc[i][5], acc[i][6], acc[i][7]);
        }
    }
}

// ===========================================================================
// STAGE 2: role E (blocks 0..511) = fused dwconv+silu -> xc, projections
//          role B (blocks 512..527) = expert-mixes (sums partial means)
// ===========================================================================
__global__ __launch_bounds__(256) void k_stage2(
    const float* __restrict__ xi,
    const float* __restrict__ cw, const float* __restrict__ cb,
    const float* __restrict__ xpw,
    float* __restrict__ xc, float4* __restrict__ proj4, float2* __restrict__ projBC,
    const float* __restrict__ meanp,
    const float* __restrict__ ew3, const float* __restrict__ gw3, const float* __restrict__ g13,
    const float* __restrict__ ew5, const float* __restrict__ gw5, const float* __restrict__ g15,
    const float* __restrict__ ew7, const float* __restrict__ gw7, const float* __restrict__ g17,
    float* __restrict__ w3o, float* __restrict__ w5o, float* __restrict__ w7o) {
    __shared__ float smem[12608];
    int bid = blockIdx.x;
    int tid = threadIdx.x;

    if (bid < 512) {
        // ---------------- role E: k_convproj ----------------
        int h0 = (bid & 31) * 2;
        int b  = bid >> 5;
        float* xs  = smem;                 // 32*264 = 8448
        float* xcs = smem + 8448;          // 32*130 = 4160

        int dir = tid >> 7;
        int px  = tid & 127;
        float acc0 = 0.f, acc1 = 0.f, acc2 = 0.f, acc3 = 0.f, acc4 = 0.f, acc5 = 0.f;

        int cl_c = tid >> 3;
        int p0_c = (tid & 7) * 16;
        int row_c = p0_c >> 6;
        int wb_c  = p0_c & 63;

        for (int ch0 = 0; ch0 < 64; ch0 += 32) {
            if (ch0) __syncthreads();
            {
                int s = tid;
#pragma unroll
                for (int it = 0; it < 8; ++it, s += 256) {
                    int c = s >> 6;
                    int rem = s & 63;
                    int r = rem >> 4, w4 = (rem & 15) * 4;
                    int gh = h0 - 1 + r;
                    float4 v = make_float4(0.f, 0.f, 0.f, 0.f);
                    if (gh >= 0 && gh < 64)
                        v = *(const float4*)(xi + ((size_t)b * 64 + ch0 + c) * HW + gh * 64 + w4);
                    float* dp = xs + c * 264 + r * 66 + 1 + w4;
                    dp[0] = v.x; dp[1] = v.y; dp[2] = v.z; dp[3] = v.w;
                }
                if (tid < 128) {
                    int cl = tid >> 2, r = tid & 3;
                    xs[cl * 264 + r * 66 + 0]  = 0.f;
                    xs[cl * 264 + r * 66 + 65] = 0.f;
                }
            }
            __syncthreads();

            {
                float wk[9];
#pragma unroll
                for (int j = 0; j < 9; ++j) wk[j] = cw[(ch0 + cl_c) * 9 + j];
                float bias = cb[ch0 + cl_c];
                float accr[16];
#pragma unroll
                for (int k = 0; k < 16; ++k) accr[k] = bias;
#pragma unroll
                for (int dy = 0; dy < 3; ++dy) {
                    const float* rp = xs + cl_c * 264 + (row_c + dy) * 66 + wb_c;
                    float r[18];
#pragma unroll
                    for (int q = 0; q < 18; ++q) r[q] = rp[q];
#pragma unroll
                    for (int k = 0; k < 16; ++k)
#pragma unroll
                        for (int dx = 0; dx < 3; ++dx)
                            accr[k] = fmaf(r[k + dx], wk[dy * 3 + dx], accr[k]);
                }
#pragma unroll
                for (int k = 0; k < 16; ++k)
                    xcs[cl_c * 130 + p0_c + k] = silu_f(accr[k]);
            }
            __syncthreads();

            {
                int s = tid;
#pragma unroll
                for (int it = 0; it < 4; ++it, s += 256) {
                    int c = s >> 5, pq = (s & 31) * 4;
                    const float* sp = xcs + c * 130 + pq;
                    *(float4*)(xc + ((size_t)b * 64 + ch0 + c) * HW + h0 * 64 + pq) =
                        make_float4(sp[0], sp[1], sp[2], sp[3]);
                }
            }
            {
                const float* wp = xpw + dir * 6 * 64 + ch0;
#pragma unroll 8
                for (int c = 0; c < 32; ++c) {
                    float xv = xcs[c * 130 + px];
                    acc0 = fmaf(xv, wp[0 * 64 + c], acc0);
                    acc1 = fmaf(xv, wp[1 * 64 + c], acc1);
                    acc2 = fmaf(xv, wp[2 * 64 + c], acc2);
                    acc3 = fmaf(xv, wp[3 * 64 + c], acc3);
                    acc4 = fmaf(xv, wp[4 * 64 + c], acc4);
                    acc5 = fmaf(xv, wp[5 * 64 + c], acc5);
                }
            }
        }

        int h = h0 + (px >> 6), w = px & 63;
        int l = (dir == 0) ? (h * 64 + w) : (w * 64 + h);
        size_t base = ((size_t)dir * NB + b) * HW + l;
        proj4[base]  = make_float4(acc0, acc1, acc2, acc3);
        projBC[base] = make_float2(acc4, acc5);
    } else {
        // ---------------- role B: k_weff_all ----------------
        int b = bid - 512;
        int c = tid;
        float* m = smem;
        float* g = smem + 64;
        if (c < 64) m[c] = meanp[b * 64 + c] + meanp[1024 + b * 64 + c];
        __syncthreads();
        const float rs = rsqrtf(1.f + 1e-5f);

#define WEFF_SECT(GW, EW, G1, OUT, K2)                                        \
        {                                                                     \
            if (c < 4) {                                                      \
                float l = 0.f;                                                \
                for (int cc = 0; cc < 64; ++cc) l += m[cc] * GW[c * 64 + cc]; \
                g[c] = l;                                                     \
            }                                                                 \
            __syncthreads();                                                  \
            if (c == 0) {                                                     \
                float mx = fmaxf(fmaxf(g[0], g[1]), fmaxf(g[2], g[3]));       \
                float e0 = expf(g[0] - mx), e1 = expf(g[1] - mx);             \
                float e2 = expf(g[2] - mx), e3 = expf(g[3] - mx);             \
                float inv = 1.f / (e0 + e1 + e2 + e3);                        \
                g[0] = e0 * inv; g[1] = e1 * inv; g[2] = e2 * inv; g[3] = e3 * inv; \
            }                                                                 \
            __syncthreads();                                                  \
            if (c < 64) {                                                     \
                float g1s = G1[c] * rs;                                       \
                for (int kk = 0; kk < K2; ++kk) {                             \
                    float w = 0.f;                                            \
                    for (int e = 0; e < 4; ++e) w += g[e] * EW[(e * 64 + c) * K2 + kk]; \
                    OUT[(b * 64 + c) * K2 + kk] = w * g1s;                    \
                }                                                             \
            }                                                                 \
            __syncthreads();                                                  \
        }

        WEFF_SECT(gw3, ew3, g13, w3o, 9)
        WEFF_SECT(gw5, ew5, g15, w5o, 25)
        WEFF_SECT(gw7, ew7, g17, w7o, 49)
#undef WEFF_SECT
    }
}

// ===========================================================================
// STAGE 3: selective scan, both directions per block (unchanged).
// ===========================================================================
__global__ __launch_bounds__(256) void k_scan2(const float* __restrict__ xc,
                                               const float4* __restrict__ proj4,
                                               const float2* __restrict__ projBC,
                                               const float* __restrict__ dt_w,
                                               const float* __restrict__ dt_b,
                                               const float* __restrict__ A_log,
                                               const float* __restrict__ Dp,
                                               const float* __restrict__ z,
                                               float* __restrict__ yz) {
    int wave = threadIdx.x >> 6;
    int lane = threadIdx.x & 63;
    int wid = blockIdx.x;                // b*64 + d
    int b = wid >> 6;
    int d = wid & 63;

    __shared__ float ut[64 * 65];
    __shared__ float al[4][1088];
    __shared__ float bl[4][1088];
    __shared__ float aggA[4], aggB[4];

    const float* uplane = xc + ((size_t)b * 64 + d) * HW;
    const float4* up4 = (const float4*)uplane;
#pragma unroll
    for (int q = 0; q < 4; ++q) {
        int s = q * 256 + threadIdx.x;
        float4 v = up4[s];
        int r = s >> 4, c0 = (s & 15) * 4;
        float* p = ut + r * 65 + c0;
        p[0] = v.x; p[1] = v.y; p[2] = v.z; p[3] = v.w;
    }
    __syncthreads();

    int ch = wave;
    float* a_my = al[wave];
    float* b_my = bl[wave];
    float y0r[16];

    // ================= DIR 0 =================
    {
        float4 wv = *(const float4*)(dt_w + d * 4);
        float db = dt_b[d];
        float A = -__expf(A_log[d]);
        float Dv = Dp[d];
        const float4* p4 = proj4 + (size_t)b * HW;
        const float2* pBC = projBC + (size_t)b * HW;

        float uv[16], cm[16];
#pragma unroll
        for (int j = 0; j < 16; ++j) {
            int el = j * 64 + lane;
            int e  = ch * 1024 + el;
            float4 t4 = p4[e];
            float2 t2 = pBC[e];
            float u = ut[(ch * 16 + j) * 65 + lane];
            uv[j] = u; cm[j] = t2.y;
            float pre = fmaf(t4.x, wv.x, fmaf(t4.y, wv.y,
                        fmaf(t4.z, wv.z, fmaf(t4.w, wv.w, db))));
            float delta = softplus_fast(pre);
            float aj = __expf(delta * A);
            float bj = delta * t2.x * u;
            int idx = (el >> 4) * 17 + (el & 15);
            a_my[idx] = aj;
            b_my[idx] = bj;
        }
        __builtin_amdgcn_wave_barrier();

        float a[16], bb[16];
#pragma unroll
        for (int j = 0; j < 16; ++j) {
            a[j]  = a_my[lane * 17 + j];
            bb[j] = b_my[lane * 17 + j];
        }
        float As = 1.f, Bs = 0.f;
#pragma unroll
        for (int j = 0; j < 16; ++j) { Bs = fmaf(a[j], Bs, bb[j]); As *= a[j]; }
        float Ai = As, Bi = Bs;
#pragma unroll
        for (int off = 1; off < 64; off <<= 1) {
            float ap = __shfl_up(Ai, (unsigned)off, 64);
            float bp = __shfl_up(Bi, (unsigned)off, 64);
            if (lane >= off) { Bi = fmaf(Ai, bp, Bi); Ai *= ap; }
        }
        if (lane == 63) { aggA[wave] = Ai; aggB[wave] = Bi; }
        __syncthreads();
        float carry = 0.f;
        for (int k = 0; k < wave; ++k) carry = fmaf(aggA[k], carry, aggB[k]);
        float ap1 = __shfl_up(Ai, 1, 64);
        float bp1 = __shfl_up(Bi, 1, 64);
        float h = (lane == 0) ? carry : fmaf(ap1, carry, bp1);
#pragma unroll
        for (int j = 0; j < 16; ++j) {
            h = fmaf(a[j], h, bb[j]);
            a_my[lane * 17 + j] = h;
        }
        __builtin_amdgcn_wave_barrier();
#pragma unroll
        for (int j = 0; j < 16; ++j) {
            int el = j * 64 + lane;
            float hv = a_my[(el >> 4) * 17 + (el & 15)];
            y0r[j] = fmaf(hv, cm[j], Dv * uv[j]);
        }
    }
    __syncthreads();

    // ================= DIR 1 =================
    {
        int pd = 64 + d;
        float4 wv = *(const float4*)(dt_w + pd * 4);
        float db = dt_b[pd];
        float A = -__expf(A_log[pd]);
        float Dv = Dp[pd];
        const float4* p4 = proj4 + ((size_t)NB + b) * HW;
        const float2* pBC = projBC + ((size_t)NB + b) * HW;

        float uv[16], cm[16];
#pragma unroll
        for (int j = 0; j < 16; ++j) {
            int el = j * 64 + lane;
            int e  = ch * 1024 + el;
            float4 t4 = p4[e];
            float2 t2 = pBC[e];
            float u = ut[lane * 65 + (ch * 16 + j)];
            uv[j] = u; cm[j] = t2.y;
            float pre = fmaf(t4.x, wv.x, fmaf(t4.y, wv.y,
                        fmaf(t4.z, wv.z, fmaf(t4.w, wv.w, db))));
            float delta = softplus_fast(pre);
            float aj = __expf(delta * A);
            float bj = delta * t2.x * u;
            int idx = (el >> 4) * 17 + (el & 15);
            a_my[idx] = aj;
            b_my[idx] = bj;
        }
        __builtin_amdgcn_wave_barrier();

        float a[16], bb[16];
#pragma unroll
        for (int j = 0; j < 16; ++j) {
            a[j]  = a_my[lane * 17 + j];
            bb[j] = b_my[lane * 17 + j];
        }
        float As = 1.f, Bs = 0.f;
#pragma unroll
        for (int j = 0; j < 16; ++j) { Bs = fmaf(a[j], Bs, bb[j]); As *= a[j]; }
        float Ai = As, Bi = Bs;
#pragma unroll
        for (int off = 1; off < 64; off <<= 1) {
            float ap = __shfl_up(Ai, (unsigned)off, 64);
            float bp = __shfl_up(Bi, (unsigned)off, 64);
            if (lane >= off) { Bi = fmaf(Ai, bp, Bi); Ai *= ap; }
        }
        if (lane == 63) { aggA[wave] = Ai; aggB[wave] = Bi; }
        __syncthreads();
        float carry = 0.f;
        for (int k = 0; k < wave; ++k) carry = fmaf(aggA[k], carry, aggB[k]);
        float ap1 = __shfl_up(Ai, 1, 64);
        float bp1 = __shfl_up(Bi, 1, 64);
        float h = (lane == 0) ? carry : fmaf(ap1, carry, bp1);
#pragma unroll
        for (int j = 0; j < 16; ++j) {
            h = fmaf(a[j], h, bb[j]);
            a_my[lane * 17 + j] = h;
        }
        __builtin_amdgcn_wave_barrier();
#pragma unroll
        for (int j = 0; j < 16; ++j) {
            int el = j * 64 + lane;
            float hv = a_my[(el >> 4) * 17 + (el & 15)];
            ut[lane * 65 + (ch * 16 + j)] = fmaf(hv, cm[j], Dv * uv[j]);
        }
    }
    __syncthreads();

    const float* zp = z + ((size_t)b * 64 + d) * HW;
    float* yp = yz + ((size_t)b * 64 + d) * HW;
#pragma unroll
    for (int j = 0; j < 16; ++j) {
        int e = ch * 1024 + j * 64 + lane;
        float y1v = ut[(ch * 16 + j) * 65 + lane];
        float zz = zp[e];
        yp[e] = (y0r[j] + y1v) * silu_f(zz);
    }
}

// ===========================================================================
// STAGE 4 (roles interleaved: bid%5==4 -> G, else C)
//   role C = local conv, 2-output-row groups w/ shared window rows
//            + passthrough copy (out channels [64:256]). 2048 blocks.
//   role G = final GEMM (wt o-index XOR-swizzled) + up add (out [0:64]).
// ===========================================================================
__global__ __launch_bounds__(256) void k_stage4(
    const float* __restrict__ x,
    const float* __restrict__ w3, const float* __restrict__ w5, const float* __restrict__ w7,
    const float* __restrict__ b1_0, const float* __restrict__ pw0,
    const float* __restrict__ g2_0, const float* __restrict__ b2_0,
    const float* __restrict__ b1_1, const float* __restrict__ pw1,
    const float* __restrict__ g2_1, const float* __restrict__ b2_1,
    const float* __restrict__ b1_2, const float* __restrict__ pw2,
    const float* __restrict__ g2_2, const float* __restrict__ b2_2,
    const float* __restrict__ yz, const float* __restrict__ ow,
    const float* __restrict__ base_scale, const float* __restrict__ up,
    float* __restrict__ out) {
    __shared__ float smem[6144];
    int bid = blockIdx.x;
    int tid = threadIdx.x;

    if (bid % 5 != 4) {
        // ---------------- role C: 32-row half-plane conv ----------------
        int cidx = (bid / 5) * 4 + (bid % 5);   // 0..2047
        int half = cidx & 1;
        int c = (cidx >> 1) & 63;
        int b = cidx >> 7;
        int oy = half * 32;
        float* t = smem;                   // 38 rows x 72 stride = 2736 floats
        const float* xp = x + ((size_t)b * DIM + 64 + c) * HW;

        // zero pass
        {
            float4 z4 = make_float4(0.f, 0.f, 0.f, 0.f);
            for (int i = tid; i < 684; i += 256) ((float4*)t)[i] = z4;
        }
        // fused passthrough copy
        {
            const float4* x4 = (const float4*)x;
            float4* o4 = (float4*)out;
            int base = cidx * 1024;
#pragma unroll
            for (int it = 0; it < 4; ++it) {
                int idx = base + it * 256 + tid;
                int bb = idx >> 17;
                int r  = idx & 131071;
                int gi = bb * 262144 + 131072 + r;
                o4[gi] = x4[gi];
            }
        }
        __syncthreads();
        // data pass: rows -3..34 (tile rows 0..37), data at cols 4..67
        {
            for (int i = tid; i < 608; i += 256) {
                int tr = i >> 4, q = (i & 15) * 4;
                int gy = oy + tr - 3;
                if (gy >= 0 && gy < 64)
                    *(float4*)(t + tr * 72 + 4 + q) = *(const float4*)(xp + gy * 64 + q);
            }
        }
        const float* w3p = w3 + (b * 64 + c) * 9;
        const float* w5p = w5 + (b * 64 + c) * 25;
        const float* w7p = w7 + (b * 64 + c) * 49;
        float W3r[9], W5r[25], W7r[49];
#pragma unroll
        for (int j = 0; j < 9; ++j)  W3r[j] = w3p[j];
#pragma unroll
        for (int j = 0; j < 25; ++j) W5r[j] = w5p[j];
#pragma unroll
        for (int j = 0; j < 49; ++j) W7r[j] = w7p[j];
        __syncthreads();

        const float rs = rsqrtf(1.f + 1e-5f);
        float bb1a = b1_0[c], bb1b = b1_1[c], bb1c = b1_2[c];
        float ssa = pw0[c] * g2_0[c] * rs, ssb = pw1[c] * g2_1[c] * rs, ssc = pw2[c] * g2_2[c] * rs;
        float bb2a = b2_0[c], bb2b = b2_1[c], bb2c = b2_2[c];

        int r  = tid >> 4;
        int x0 = (tid & 15) * 4;

        float a3[2][4] = {{0.f,0.f,0.f,0.f},{0.f,0.f,0.f,0.f}};
        float a5[2][4] = {{0.f,0.f,0.f,0.f},{0.f,0.f,0.f,0.f}};
        float a7[2][4] = {{0.f,0.f,0.f,0.f},{0.f,0.f,0.f,0.f}};

#pragma unroll
        for (int j = 0; j < 8; ++j) {
            const float4* rp = (const float4*)(t + (2 * r + j) * 72 + x0);
            float4 q0 = rp[0], q1 = rp[1], q2 = rp[2];
            float rr[12] = {q0.x, q0.y, q0.z, q0.w, q1.x, q1.y, q1.z, q1.w,
                            q2.x, q2.y, q2.z, q2.w};
            if (j <= 6) {
#pragma unroll
                for (int k = 0; k < 4; ++k)
#pragma unroll
                    for (int dx = 0; dx < 7; ++dx)
                        a7[0][k] = fmaf(rr[k + dx + 1], W7r[j * 7 + dx], a7[0][k]);
                if (j >= 1 && j <= 5) {
#pragma unroll
                    for (int k = 0; k < 4; ++k)
#pragma unroll
                        for (int dx = 0; dx < 5; ++dx)
                            a5[0][k] = fmaf(rr[k + dx + 2], W5r[(j - 1) * 5 + dx], a5[0][k]);
                }
                if (j >= 2 && j <= 4) {
#pragma unroll
                    for (int k = 0; k < 4; ++k)
#pragma unroll
                        for (int dx = 0; dx < 3; ++dx)
                            a3[0][k] = fmaf(rr[k + dx + 3], W3r[(j - 2) * 3 + dx], a3[0][k]);
                }
            }
            if (j >= 1) {
#pragma unroll
                for (int k = 0; k < 4; ++k)
#pragma unroll
                    for (int dx = 0; dx < 7; ++dx)
                        a7[1][k] = fmaf(rr[k + dx + 1], W7r[(j - 1) * 7 + dx], a7[1][k]);
                if (j >= 2 && j <= 6) {
#pragma unroll
                    for (int k = 0; k < 4; ++k)
#pragma unroll
                        for (int dx = 0; dx < 5; ++dx)
                            a5[1][k] = fmaf(rr[k + dx + 2], W5r[(j - 2) * 5 + dx], a5[1][k]);
                }
                if (j >= 3 && j <= 5) {
#pragma unroll
                    for (int k = 0; k < 4; ++k)
#pragma unroll
                        for (int dx = 0; dx < 3; ++dx)
                            a3[1][k] = fmaf(rr[k + dx + 3], W3r[(j - 3) * 3 + dx], a3[1][k]);
                }
            }
        }

        float* op = out + ((size_t)b * DIM + 64 + c) * HW;
#pragma unroll
        for (int rr2 = 0; rr2 < 2; ++rr2) {
            float4 res;
            float* rv = (float*)&res;
#pragma unroll
            for (int k = 0; k < 4; ++k) {
                rv[k] = mish_fast(a3[rr2][k] + bb1a) * ssa + bb2a
                      + mish_fast(a5[rr2][k] + bb1b) * ssb + bb2b
                      + mish_fast(a7[rr2][k] + bb1c) * ssc + bb2c;
            }
            *(float4*)(op + (oy + 2 * r + rr2) * 64 + x0) = res;
        }
    } else {
        // ---------------- role G: k_final ----------------
        int id2 = bid / 5;                 // 0..511
        int h0 = (id2 & 31) * 2;
        int b  = id2 >> 5;
        float* yv = smem;                  // 32*128 = 4096
        float* wt = smem + 4096;           // 32*64 = 2048, o-index swizzled

        float acc[8][4];
#pragma unroll
        for (int i = 0; i < 8; ++i)
#pragma unroll
            for (int j = 0; j < 4; ++j) acc[i][j] = 0.f;

        int o0 = (tid >> 5) * 8;
        int p0 = (tid & 31) * 4;

        for (int ko = 0; ko < 64; ko += 32) {
            if (ko) __syncthreads();
            {
                int s = tid;
#pragma unroll
                for (int it = 0; it < 4; ++it, s += 256) {
                    int c = s >> 5, p4 = (s & 31) * 4;
                    size_t idx = ((size_t)b * 64 + ko + c) * HW + h0 * 64 + p4;
                    *(float4*)(yv + c * 128 + p4) = *(const float4*)(yz + idx);
                }
            }
            {
                int s = tid;
#pragma unroll
                for (int it = 0; it < 2; ++it, s += 256) {
                    int o = s >> 3, c0 = (s & 7) * 4;
#pragma unroll
                    for (int i = 0; i < 4; ++i) {
                        int cc = c0 + i;
                        int osw = o ^ (((cc >> 2) & 3) << 3);
                        wt[cc * 64 + osw] = ((const float*)(ow + o * 64 + ko + c0))[i];
                    }
                }
            }
            __syncthreads();
#pragma unroll 4
            for (int c = 0; c < 32; ++c) {
                int osw = o0 ^ (((c >> 2) & 3) << 3);
                float wv[8], xv[4];
                *(float4*)(wv)     = *(const float4*)(wt + c * 64 + osw);
                *(float4*)(wv + 4) = *(const float4*)(wt + c * 64 + osw + 4);
                *(float4*)(xv)     = *(const float4*)(yv + c * 128 + p0);
#pragma unroll
                for (int i = 0; i < 8; ++i)
#pragma unroll
                    for (int j = 0; j < 4; ++j)
                        acc[i][j] = fmaf(wv[i], xv[j], acc[i][j]);
            }
        }

#pragma unroll
        for (int i = 0; i < 8; ++i) {
            int o = o0 + i;
            float bs = base_scale[o];
            float4 u = *(const float4*)(up + ((size_t)b * 64 + o) * HW + h0 * 64 + p0);
            float4 r = make_float4(fmaf(bs, acc[i][0], u.x),
                                   fmaf(bs, acc[i][1], u.y),
                                   fmaf(bs, acc[i][2], u.z),
                                   fmaf(bs, acc[i][3], u.w));
            *(float4*)(out + ((size_t)b * DIM + o) * HW + h0 * 64 + p0) = r;
        }
    }
}

// ---------------------------------------------------------------------------
extern "C" void kernel_launch(void* const* d_in, const int* in_sizes, int n_in,
                              void* d_out, int out_size, void* d_ws, size_t ws_size,
                              hipStream_t stream) {
    (void)in_sizes; (void)n_in; (void)out_size; (void)ws_size;
    const float* x = (const float*)d_in[0];
    float* out = (float*)d_out;
    float* ws = (float*)d_ws;

    const size_t IMG = (size_t)NB * 64 * HW;   // 4,194,304 floats
    float* buf_xi   = ws;                      // xi, later reused as yz
    float* buf_z    = ws + IMG;
    float* buf_xc   = ws + 2 * IMG;
    float* buf_up   = ws + 3 * IMG;
    float* buf_p4   = ws + 4 * IMG;            // float4[2*16*4096]
    float* buf_pBC  = buf_p4 + (size_t)4 * 2 * NB * HW;
    float* buf_mean = buf_pBC + (size_t)2 * 2 * NB * HW;   // 2048 (two halves)
    float* buf_w3   = buf_mean + 2048;
    float* buf_w5   = buf_w3 + 16 * 64 * 9;
    float* buf_w7   = buf_w5 + 16 * 64 * 25;

    // stage1: wavelet-up halves + partial means (A) || input projection (D)
    k_stage1<<<2560, 256, 0, stream>>>(x,
        (const float*)d_in[22], (const float*)d_in[23], (const float*)d_in[24],
        buf_up, buf_mean,
        (const float*)d_in[26], buf_xi, buf_z);

    // stage2: dwconv+proj (E) || expert-mix weights (B)
    k_stage2<<<528, 256, 0, stream>>>(buf_xi,
        (const float*)d_in[27], (const float*)d_in[28], (const float*)d_in[29],
        buf_xc, (float4*)buf_p4, (float2*)buf_pBC,
        buf_mean,
        (const float*)d_in[1],  (const float*)d_in[2],  (const float*)d_in[3],
        (const float*)d_in[8],  (const float*)d_in[9],  (const float*)d_in[10],
        (const float*)d_in[15], (const float*)d_in[16], (const float*)d_in[17],
        buf_w3, buf_w5, buf_w7);

    // stage3: dual-direction selective scan -> yz (xi is dead, reuse)
    k_scan2<<<1024, 256, 0, stream>>>(buf_xc, (const float4*)buf_p4, (const float2*)buf_pBC,
        (const float*)d_in[30], (const float*)d_in[31],
        (const float*)d_in[32], (const float*)d_in[33],
        buf_z, buf_xi);

    // stage4: local conv + passthrough (C) || final GEMM (G), interleaved
    k_stage4<<<2560, 256, 0, stream>>>(x, buf_w3, buf_w5, buf_w7,
        (const float*)d_in[4],  (const float*)d_in[5],  (const float*)d_in[6],  (const float*)d_in[7],
        (const float*)d_in[11], (const float*)d_in[12], (const float*)d_in[13], (const float*)d_in[14],
        (const float*)d_in[18], (const float*)d_in[19], (const float*)d_in[20], (const float*)d_in[21],
        buf_xi, (const float*)d_in[34], (const float*)d_in[25], buf_up, out);
}